// Round 1
// baseline (22327.132 us; speedup 1.0000x reference)
//
#include <hip/hip_runtime.h>
#include <hip/hip_bf16.h>
#include <math.h>

typedef __hip_bfloat16 bf16;
typedef __attribute__((ext_vector_type(8))) short          s16x8;   // MFMA a/b frag (8 bf16)
typedef __attribute__((ext_vector_type(8))) unsigned short u16x8;
typedef __attribute__((ext_vector_type(4))) float          f32x4;   // MFMA acc

#define B_   4
#define S_   1024
#define D_   512
#define H_   8
#define DK_  64
#define DFF_ 2048
#define L_   6
#define V_   16000
#define NT_  (B_ * S_)   // 4096 tokens

// Runtime dtype flag: 1 if float tensors are bf16 on device, 0 if f32.
// Detected from enc_ln_g (all ones): bf16 -> first two u16 both 0x3F80.
__global__ void detect_kernel(const void* __restrict__ g, int* __restrict__ flag)
{
    const unsigned short* u = (const unsigned short*)g;
    *flag = (u[0] == 0x3F80 && u[1] == 0x3F80) ? 1 : 0;
}

__device__ __forceinline__ float ldw(const void* p, size_t i, int isbf)
{
    if (isbf) return __bfloat162float(((const bf16*)p)[i]);
    return ((const float*)p)[i];
}

// f32 -> bf16 bits, round-to-nearest-even
__device__ __forceinline__ unsigned short f2b(float f)
{
    unsigned int u = __float_as_uint(f);
    return (unsigned short)((u + 0x7FFFu + ((u >> 16) & 1u)) >> 16);
}

// ---------------------------------------------------------------------------
// Embedding + positional encoding: X[bs,d] = emb[tok[bs]][d] + pe(s,d)
// ---------------------------------------------------------------------------
__global__ __launch_bounds__(256)
void embed_kernel(const int* __restrict__ tok, const void* __restrict__ emb,
                  float* __restrict__ X, const int* __restrict__ flagp)
{
    const int isbf = *flagp;
    int idx = blockIdx.x * 256 + threadIdx.x;      // < NT_*D_ (exact multiple)
    int d  = idx & (D_ - 1);
    int bs = idx >> 9;                              // D_=512 -> shift 9
    int s  = bs & (S_ - 1);
    int t  = tok[bs];
    float e = ldw(emb, (size_t)t * D_ + d, isbf);
    float expo = (float)(d & ~1) * (1.0f / (float)D_);
    float div  = powf(10000.0f, expo);
    float arg  = (float)s / div;
    float pe   = (d & 1) ? cosf(arg) : sinf(arg);
    X[idx] = e + pe;
}

// ---------------------------------------------------------------------------
// MFMA GEMM: C[M,N] = A[M,K](f32) * W[K,N](flag dtype) + bias [+res] [relu]
//   - 256 threads = 4 waves in 2x2; per-wave tile (BM/2)x(BN/2); BK=32.
//   - A reg-staged with f32->bf16 convert; W transpose-staged to Bs[n][k].
//   - LDS rows padded to 40 ushorts (80 B): ds_read_b128 fragment loads are
//     2-way bank-aliased (free).  A/B frags use identical (lane,reg)->k
//     mapping (k-permutation invariant), C/D: col=lane&15, row=(lane>>4)*4+q.
//   - blockIdx.z batches weight matrices sharing the same A (QKV fusion).
// ---------------------------------------------------------------------------
template<int BM, int BN>
__global__ __launch_bounds__(256)
void gemm_mfma_kernel(const float* __restrict__ A,
                      const void* __restrict__ W, size_t w_off,
                      const void* __restrict__ bias, size_t b_off,
                      const float* __restrict__ res,
                      float* __restrict__ Cf, void* __restrict__ Cout,
                      int M, int N, int K, int relu,
                      size_t sW, size_t sO, size_t sB,
                      const int* __restrict__ flagp)
{
    constexpr int ROWU = 40;          // ushorts per LDS row: 32 k + 8 pad
    constexpr int FM = BM / 32;       // 16x16 frags per wave, m-dir
    constexpr int FN = BN / 32;       // 16x16 frags per wave, n-dir
    __shared__ __align__(16) unsigned short As[BM * ROWU];
    __shared__ __align__(16) unsigned short Bs[BN * ROWU];

    const int isbf = *flagp;
    const int tid  = threadIdx.x;
    const int lane = tid & 63;
    const int wid  = tid >> 6;
    const int wr   = wid >> 1, wc = wid & 1;
    const int l15  = lane & 15, g = lane >> 4;
    const int row0 = blockIdx.y * BM;
    const int col0 = blockIdx.x * BN;
    const int z    = blockIdx.z;
    const size_t wbase = w_off + (size_t)z * sW;

    f32x4 acc[FM][FN];
#pragma unroll
    for (int i = 0; i < FM; ++i)
#pragma unroll
        for (int j = 0; j < FN; ++j)
            acc[i][j] = (f32x4){0.f, 0.f, 0.f, 0.f};

    for (int k0 = 0; k0 < K; k0 += 32) {
        // ---- stage A: BM x 32 f32 -> bf16 ----
#pragma unroll
        for (int u = 0; u < (BM * 4) / 256; ++u) {
            int unit = tid + u * 256;            // 8 consecutive k's
            int r = unit >> 2, q = unit & 3;
            const float* ap = A + (size_t)(row0 + r) * K + k0 + q * 8;
            float4 f0 = *(const float4*)ap;
            float4 f1 = *(const float4*)(ap + 4);
            u16x8 v;
            v[0] = f2b(f0.x); v[1] = f2b(f0.y); v[2] = f2b(f0.z); v[3] = f2b(f0.w);
            v[4] = f2b(f1.x); v[5] = f2b(f1.y); v[6] = f2b(f1.z); v[7] = f2b(f1.w);
            *(u16x8*)&As[r * ROWU + q * 8] = v;
        }
        // ---- stage B: W[K,N] col-block, transposed -> Bs[n][k] ----
#pragma unroll
        for (int u = 0; u < (BN * 4) / 256; ++u) {
            int unit = tid + u * 256;
            int n = unit >> 2, q = unit & 3;
            u16x8 v;
            if (isbf) {
                const unsigned short* wp = (const unsigned short*)W;
#pragma unroll
                for (int j = 0; j < 8; ++j)
                    v[j] = wp[wbase + (size_t)(k0 + q * 8 + j) * N + col0 + n];
            } else {
                const float* wp = (const float*)W;
#pragma unroll
                for (int j = 0; j < 8; ++j)
                    v[j] = f2b(wp[wbase + (size_t)(k0 + q * 8 + j) * N + col0 + n]);
            }
            *(u16x8*)&Bs[n * ROWU + q * 8] = v;
        }
        __syncthreads();

        // ---- fragments + MFMA ----
        s16x8 af[FM], bfr[FN];
#pragma unroll
        for (int mi = 0; mi < FM; ++mi) {
            int r = wr * (BM / 2) + mi * 16 + l15;
            af[mi] = *(const s16x8*)&As[r * ROWU + g * 8];
        }
#pragma unroll
        for (int ni = 0; ni < FN; ++ni) {
            int c = wc * (BN / 2) + ni * 16 + l15;
            bfr[ni] = *(const s16x8*)&Bs[c * ROWU + g * 8];
        }
#pragma unroll
        for (int mi = 0; mi < FM; ++mi)
#pragma unroll
            for (int ni = 0; ni < FN; ++ni)
                acc[mi][ni] = __builtin_amdgcn_mfma_f32_16x16x32_bf16(
                    af[mi], bfr[ni], acc[mi][ni], 0, 0, 0);
        __syncthreads();
    }

    // ---- epilogue: bias (+res) (relu) -> f32 ws or dtype out ----
    float* cfz = Cf ? (Cf + (size_t)z * sO) : nullptr;
#pragma unroll
    for (int mi = 0; mi < FM; ++mi) {
#pragma unroll
        for (int ni = 0; ni < FN; ++ni) {
            int n = col0 + wc * (BN / 2) + ni * 16 + l15;
            float bv = ldw(bias, b_off + (size_t)z * sB + n, isbf);
#pragma unroll
            for (int q = 0; q < 4; ++q) {
                int m = row0 + wr * (BM / 2) + mi * 16 + g * 4 + q;
                float v = acc[mi][ni][q] + bv;
                size_t oidx = (size_t)m * N + n;
                if (res)  v += res[oidx];
                if (relu) v = fmaxf(v, 0.f);
                if (Cout) {
                    if (isbf) ((bf16*)Cout)[oidx] = __float2bfloat16(v);
                    else      ((float*)Cout)[oidx] = v;
                } else {
                    cfz[oidx] = v;
                }
            }
        }
    }
}

// ---------------------------------------------------------------------------
// Attention: one block per (q-position, head, batch). Q/K/V layout [B,S,H,DK].
// float4-vectorized QK and PV. causal => keys 0..q only. All f32 (workspace).
// ---------------------------------------------------------------------------
__global__ __launch_bounds__(256)
void attn_kernel(const float* __restrict__ Q, const float* __restrict__ Kp,
                 const float* __restrict__ Vp, float* __restrict__ O,
                 int causal)
{
    const int qpos = blockIdx.x, h = blockIdx.y, b = blockIdx.z;
    const int tid  = threadIdx.x;
    const int Lkv  = causal ? (qpos + 1) : S_;

    __shared__ float4 qs4[16];
    __shared__ float  sc[S_];
    __shared__ float  red[256];
    __shared__ float4 r4[16][17];

    const float* qrow = Q + ((size_t)(b * S_ + qpos) * H_ + h) * DK_;
    if (tid < 16) qs4[tid] = ((const float4*)qrow)[tid];
    __syncthreads();

    const float scale = 0.125f;   // 1/sqrt(64)
    float lmax = -INFINITY;
    for (int j = tid; j < Lkv; j += 256) {
        const float4* kr = (const float4*)(Kp + ((size_t)(b * S_ + j) * H_ + h) * DK_);
        float d = 0.f;
#pragma unroll
        for (int t = 0; t < 16; ++t) {
            float4 k4 = kr[t], q4 = qs4[t];
            d += q4.x * k4.x + q4.y * k4.y + q4.z * k4.z + q4.w * k4.w;
        }
        d *= scale;
        sc[j] = d;
        lmax = fmaxf(lmax, d);
    }
    red[tid] = lmax;
    __syncthreads();
    for (int s = 128; s > 0; s >>= 1) {
        if (tid < s) red[tid] = fmaxf(red[tid], red[tid + s]);
        __syncthreads();
    }
    float mx = red[0];
    __syncthreads();

    float lsum = 0.f;
    for (int j = tid; j < Lkv; j += 256) {
        float p = expf(sc[j] - mx);
        sc[j] = p;
        lsum += p;
    }
    red[tid] = lsum;
    __syncthreads();
    for (int s = 128; s > 0; s >>= 1) {
        if (tid < s) red[tid] += red[tid + s];
        __syncthreads();
    }
    float inv = 1.0f / red[0];
    __syncthreads();

    // PV: thread -> (d-group dg: 4 contiguous d) x (partial part over j)
    const int dg = tid & 15, part = tid >> 4;
    float4 acc = {0.f, 0.f, 0.f, 0.f};
    for (int j = part; j < Lkv; j += 16) {
        float p = sc[j];
        float4 v4 = *(const float4*)&Vp[((size_t)(b * S_ + j) * H_ + h) * DK_ + dg * 4];
        acc.x += p * v4.x; acc.y += p * v4.y; acc.z += p * v4.z; acc.w += p * v4.w;
    }
    r4[part][dg] = acc;
    __syncthreads();
    if (tid < 16) {
        float4 o = r4[0][tid];
#pragma unroll
        for (int p2 = 1; p2 < 16; ++p2) {
            float4 t4 = r4[p2][tid];
            o.x += t4.x; o.y += t4.y; o.z += t4.z; o.w += t4.w;
        }
        o.x *= inv; o.y *= inv; o.z *= inv; o.w *= inv;
        *(float4*)&O[((size_t)(b * S_ + qpos) * H_ + h) * DK_ + tid * 4] = o;
    }
}

// ---------------------------------------------------------------------------
// LayerNorm over rows of 512. One block per row. eps = 1e-5.
// ---------------------------------------------------------------------------
__global__ __launch_bounds__(256)
void layernorm_kernel(const float* __restrict__ X,
                      const void* __restrict__ g, size_t g_off,
                      const void* __restrict__ bb, size_t b_off,
                      float* __restrict__ Y, const int* __restrict__ flagp)
{
    __shared__ float red[256];
    const int isbf = *flagp;
    const int row = blockIdx.x, tid = threadIdx.x;
    const float* x = X + (size_t)row * D_;
    float v0 = x[tid], v1 = x[tid + 256];
    red[tid] = v0 + v1;
    __syncthreads();
    for (int s = 128; s > 0; s >>= 1) {
        if (tid < s) red[tid] += red[tid + s];
        __syncthreads();
    }
    float mean = red[0] * (1.0f / (float)D_);
    __syncthreads();
    float d0 = v0 - mean, d1 = v1 - mean;
    red[tid] = d0 * d0 + d1 * d1;
    __syncthreads();
    for (int s = 128; s > 0; s >>= 1) {
        if (tid < s) red[tid] += red[tid + s];
        __syncthreads();
    }
    float r = rsqrtf(red[0] * (1.0f / (float)D_) + 1e-5f);
    float* y = Y + (size_t)row * D_;
    y[tid]       = ldw(g, g_off + tid, isbf)       * d0 * r + ldw(bb, b_off + tid, isbf);
    y[tid + 256] = ldw(g, g_off + tid + 256, isbf) * d1 * r + ldw(bb, b_off + tid + 256, isbf);
}

// ---------------------------------------------------------------------------
extern "C" void kernel_launch(void* const* d_in, const int* in_sizes, int n_in,
                              void* d_out, int out_size, void* d_ws, size_t ws_size,
                              hipStream_t stream)
{
    (void)in_sizes; (void)n_in; (void)out_size;

    const int*  src      = (const int*)d_in[0];
    const int*  tgt      = (const int*)d_in[1];
    // d_in[2] = tgt_mask: deterministic causal triu -> recomputed, never read
    const void* src_emb  = d_in[3];
    const void* tgt_emb  = d_in[4];
    const void* eaw      = d_in[5];   // [L,4,D,D]
    const void* eab      = d_in[6];   // [L,4,D]
    const void* ew1      = d_in[7];   // [L,D,DFF]
    const void* eb1      = d_in[8];   // [L,DFF]
    const void* ew2      = d_in[9];   // [L,DFF,D]
    const void* eb2      = d_in[10];  // [L,D]
    const void* elg      = d_in[11];  // [L,2,D]
    const void* elb      = d_in[12];  // [L,2,D]
    const void* daw      = d_in[13];  // [L,8,D,D]
    const void* dab      = d_in[14];  // [L,8,D]
    const void* dw1      = d_in[15];
    const void* db1      = d_in[16];
    const void* dw2      = d_in[17];
    const void* db2      = d_in[18];
    const void* dlg      = d_in[19];  // [L,3,D]
    const void* dlb      = d_in[20];  // [L,3,D]
    const void* gen_w    = d_in[21];  // [D,V]
    const void* gen_b    = d_in[22];  // [V]

    // workspace carve-up (unchanged: 84 MB)
    const size_t tokD = (size_t)NT_ * D_;          // 2,097,152
    const size_t tokF = (size_t)NT_ * DFF_;        // 8,388,608
    const size_t need = 256 + (6 * tokD + tokF) * sizeof(float);
    if (ws_size < need) return;                    // visible failure, no OOB

    int*   flagp = (int*)d_ws;
    float* xbuf = (float*)((char*)d_ws + 256);     // encoder state
    float* ybuf = xbuf + tokD;         // decoder state
    float* qbuf = ybuf + tokD;         // q proj / pre-LN tmp (stride base for z)
    float* kbuf = qbuf + tokD;
    float* vbuf = kbuf + tokD;
    float* abuf = vbuf + tokD;         // attention output
    float* fbuf = abuf + tokD;         // ffn mid [NT, DFF]
    float* tbuf = qbuf;                // pre-LN tmp (q dead by then)

    detect_kernel<<<1, 1, 0, stream>>>(elg, flagp);

    // BM=64 for N=512 outputs (>=256 blocks), BM=128 for wide-N GEMMs.
    auto g64 = [&](const float* A, const void* W, size_t w_off,
                   const void* bias, size_t b_off, const float* res,
                   float* Cf, void* Cout, int M, int N, int K, int relu,
                   int nz, size_t sW, size_t sO, size_t sB) {
        dim3 grid(N / 128, M / 64, nz);
        gemm_mfma_kernel<64, 128><<<grid, 256, 0, stream>>>(
            A, W, w_off, bias, b_off, res, Cf, Cout, M, N, K, relu, sW, sO, sB, flagp);
    };
    auto g128 = [&](const float* A, const void* W, size_t w_off,
                    const void* bias, size_t b_off, const float* res,
                    float* Cf, void* Cout, int M, int N, int K, int relu,
                    int nz, size_t sW, size_t sO, size_t sB) {
        dim3 grid(N / 128, M / 128, nz);
        gemm_mfma_kernel<128, 128><<<grid, 256, 0, stream>>>(
            A, W, w_off, bias, b_off, res, Cf, Cout, M, N, K, relu, sW, sO, sB, flagp);
    };
    auto attn = [&](const float* Q, const float* Kp, const float* Vp,
                    float* O, int causal) {
        dim3 g(S_, H_, B_);
        attn_kernel<<<g, 256, 0, stream>>>(Q, Kp, Vp, O, causal);
    };
    auto ln = [&](const float* X, const void* g_, size_t g_off,
                  const void* b_, size_t b_off, float* Y) {
        layernorm_kernel<<<NT_, 256, 0, stream>>>(X, g_, g_off, b_, b_off, Y, flagp);
    };

    // ---- embeddings ----
    embed_kernel<<<(NT_ * D_) / 256, 256, 0, stream>>>(src, src_emb, xbuf, flagp);
    embed_kernel<<<(NT_ * D_) / 256, 256, 0, stream>>>(tgt, tgt_emb, ybuf, flagp);

    const size_t DD = (size_t)D_ * D_;

    // ---- encoder ----
    for (int i = 0; i < L_; ++i) {
        size_t w0 = (size_t)i * 4 * DD;
        size_t b0 = (size_t)i * 4 * D_;
        // fused QKV: z = 0,1,2 -> qbuf,kbuf,vbuf
        g64(xbuf, eaw, w0, eab, b0, nullptr, qbuf, nullptr, NT_, D_, D_, 0,
            3, DD, tokD, D_);
        attn(qbuf, kbuf, vbuf, abuf, 0);
        g64(abuf, eaw, w0 + 3 * DD, eab, b0 + 3 * D_, xbuf, tbuf, nullptr,
            NT_, D_, D_, 0, 1, 0, 0, 0);
        ln(tbuf, elg, (size_t)(i * 2 + 0) * D_, elb, (size_t)(i * 2 + 0) * D_, xbuf);
        g128(xbuf, ew1, (size_t)i * D_ * DFF_, eb1, (size_t)i * DFF_, nullptr,
             fbuf, nullptr, NT_, DFF_, D_, 1, 1, 0, 0, 0);
        g64(fbuf, ew2, (size_t)i * DFF_ * D_, eb2, (size_t)i * D_, xbuf,
            tbuf, nullptr, NT_, D_, DFF_, 0, 1, 0, 0, 0);
        ln(tbuf, elg, (size_t)(i * 2 + 1) * D_, elb, (size_t)(i * 2 + 1) * D_, xbuf);
    }

    // ---- decoder ----
    for (int i = 0; i < L_; ++i) {
        size_t w0 = (size_t)i * 8 * DD;
        size_t b0 = (size_t)i * 8 * D_;
        // masked self-attention (fused QKV)
        g64(ybuf, daw, w0, dab, b0, nullptr, qbuf, nullptr, NT_, D_, D_, 0,
            3, DD, tokD, D_);
        attn(qbuf, kbuf, vbuf, abuf, 1);
        g64(abuf, daw, w0 + 3 * DD, dab, b0 + 3 * D_, ybuf, tbuf, nullptr,
            NT_, D_, D_, 0, 1, 0, 0, 0);
        ln(tbuf, dlg, (size_t)(i * 3 + 0) * D_, dlb, (size_t)(i * 3 + 0) * D_, ybuf);
        // cross-attention: q from y; fused K,V from encoder output x
        g64(ybuf, daw, w0 + 4 * DD, dab, b0 + 4 * D_, nullptr, qbuf, nullptr,
            NT_, D_, D_, 0, 1, 0, 0, 0);
        g64(xbuf, daw, w0 + 5 * DD, dab, b0 + 5 * D_, nullptr, kbuf, nullptr,
            NT_, D_, D_, 0, 2, DD, tokD, D_);
        attn(qbuf, kbuf, vbuf, abuf, 0);
        g64(abuf, daw, w0 + 7 * DD, dab, b0 + 7 * D_, ybuf, tbuf, nullptr,
            NT_, D_, D_, 0, 1, 0, 0, 0);
        ln(tbuf, dlg, (size_t)(i * 3 + 1) * D_, dlb, (size_t)(i * 3 + 1) * D_, ybuf);
        // FFN
        g128(ybuf, dw1, (size_t)i * D_ * DFF_, db1, (size_t)i * DFF_, nullptr,
             fbuf, nullptr, NT_, DFF_, D_, 1, 1, 0, 0, 0);
        g64(fbuf, dw2, (size_t)i * DFF_ * D_, db2, (size_t)i * D_, ybuf,
            tbuf, nullptr, NT_, D_, DFF_, 0, 1, 0, 0, 0);
        ln(tbuf, dlg, (size_t)(i * 3 + 2) * D_, dlb, (size_t)(i * 3 + 2) * D_, ybuf);
    }

    // ---- generator -> d_out (dtype per flag); V=16000 = 125*128 ----
    g128(ybuf, gen_w, 0, gen_b, 0, nullptr, nullptr, d_out, NT_, V_, D_, 0,
         1, 0, 0, 0);
}

// Round 2
// 5739.435 us; speedup vs baseline: 3.8901x; 3.8901x over previous
//
#include <hip/hip_runtime.h>
#include <hip/hip_bf16.h>
#include <math.h>

typedef __hip_bfloat16 bf16;
typedef __attribute__((ext_vector_type(8))) short          s16x8;   // MFMA a/b frag (8 bf16)
typedef __attribute__((ext_vector_type(8))) unsigned short u16x8;
typedef __attribute__((ext_vector_type(4))) float          f32x4;   // MFMA acc

#define B_   4
#define S_   1024
#define D_   512
#define H_   8
#define DK_  64
#define DFF_ 2048
#define L_   6
#define V_   16000
#define NT_  (B_ * S_)   // 4096 tokens

// Runtime dtype flag: 1 if float tensors are bf16 on device, 0 if f32.
// Detected from enc_ln_g (all ones): bf16 -> first two u16 both 0x3F80.
__global__ void detect_kernel(const void* __restrict__ g, int* __restrict__ flag)
{
    const unsigned short* u = (const unsigned short*)g;
    *flag = (u[0] == 0x3F80 && u[1] == 0x3F80) ? 1 : 0;
}

__device__ __forceinline__ float ldw(const void* p, size_t i, int isbf)
{
    if (isbf) return __bfloat162float(((const bf16*)p)[i]);
    return ((const float*)p)[i];
}

// f32 -> bf16 bits, round-to-nearest-even
__device__ __forceinline__ unsigned short f2b(float f)
{
    unsigned int u = __float_as_uint(f);
    return (unsigned short)((u + 0x7FFFu + ((u >> 16) & 1u)) >> 16);
}

// ---------------------------------------------------------------------------
// Embedding + positional encoding: X[bs,d] = emb[tok[bs]][d] + pe(s,d)
// ---------------------------------------------------------------------------
__global__ __launch_bounds__(256)
void embed_kernel(const int* __restrict__ tok, const void* __restrict__ emb,
                  float* __restrict__ X, const int* __restrict__ flagp)
{
    const int isbf = *flagp;
    int idx = blockIdx.x * 256 + threadIdx.x;      // < NT_*D_ (exact multiple)
    int d  = idx & (D_ - 1);
    int bs = idx >> 9;                              // D_=512 -> shift 9
    int s  = bs & (S_ - 1);
    int t  = tok[bs];
    float e = ldw(emb, (size_t)t * D_ + d, isbf);
    float expo = (float)(d & ~1) * (1.0f / (float)D_);
    float div  = powf(10000.0f, expo);
    float arg  = (float)s / div;
    float pe   = (d & 1) ? cosf(arg) : sinf(arg);
    X[idx] = e + pe;
}

// ---------------------------------------------------------------------------
// MFMA GEMM: C[M,N] = A[M,K](f32) * W[K,N](flag dtype) + bias [+res] [relu]
//   (structure unchanged from round 1 — harness-verified)
// ---------------------------------------------------------------------------
template<int BM, int BN>
__global__ __launch_bounds__(256)
void gemm_mfma_kernel(const float* __restrict__ A,
                      const void* __restrict__ W, size_t w_off,
                      const void* __restrict__ bias, size_t b_off,
                      const float* __restrict__ res,
                      float* __restrict__ Cf, void* __restrict__ Cout,
                      int M, int N, int K, int relu,
                      size_t sW, size_t sO, size_t sB,
                      const int* __restrict__ flagp)
{
    constexpr int ROWU = 40;          // ushorts per LDS row: 32 k + 8 pad
    constexpr int FM = BM / 32;       // 16x16 frags per wave, m-dir
    constexpr int FN = BN / 32;       // 16x16 frags per wave, n-dir
    __shared__ __align__(16) unsigned short As[BM * ROWU];
    __shared__ __align__(16) unsigned short Bs[BN * ROWU];

    const int isbf = *flagp;
    const int tid  = threadIdx.x;
    const int lane = tid & 63;
    const int wid  = tid >> 6;
    const int wr   = wid >> 1, wc = wid & 1;
    const int l15  = lane & 15, g = lane >> 4;
    const int row0 = blockIdx.y * BM;
    const int col0 = blockIdx.x * BN;
    const int z    = blockIdx.z;
    const size_t wbase = w_off + (size_t)z * sW;

    f32x4 acc[FM][FN];
#pragma unroll
    for (int i = 0; i < FM; ++i)
#pragma unroll
        for (int j = 0; j < FN; ++j)
            acc[i][j] = (f32x4){0.f, 0.f, 0.f, 0.f};

    for (int k0 = 0; k0 < K; k0 += 32) {
        // ---- stage A: BM x 32 f32 -> bf16 ----
#pragma unroll
        for (int u = 0; u < (BM * 4) / 256; ++u) {
            int unit = tid + u * 256;            // 8 consecutive k's
            int r = unit >> 2, q = unit & 3;
            const float* ap = A + (size_t)(row0 + r) * K + k0 + q * 8;
            float4 f0 = *(const float4*)ap;
            float4 f1 = *(const float4*)(ap + 4);
            u16x8 v;
            v[0] = f2b(f0.x); v[1] = f2b(f0.y); v[2] = f2b(f0.z); v[3] = f2b(f0.w);
            v[4] = f2b(f1.x); v[5] = f2b(f1.y); v[6] = f2b(f1.z); v[7] = f2b(f1.w);
            *(u16x8*)&As[r * ROWU + q * 8] = v;
        }
        // ---- stage B: W[K,N] col-block, transposed -> Bs[n][k] ----
#pragma unroll
        for (int u = 0; u < (BN * 4) / 256; ++u) {
            int unit = tid + u * 256;
            int n = unit >> 2, q = unit & 3;
            u16x8 v;
            if (isbf) {
                const unsigned short* wp = (const unsigned short*)W;
#pragma unroll
                for (int j = 0; j < 8; ++j)
                    v[j] = wp[wbase + (size_t)(k0 + q * 8 + j) * N + col0 + n];
            } else {
                const float* wp = (const float*)W;
#pragma unroll
                for (int j = 0; j < 8; ++j)
                    v[j] = f2b(wp[wbase + (size_t)(k0 + q * 8 + j) * N + col0 + n]);
            }
            *(u16x8*)&Bs[n * ROWU + q * 8] = v;
        }
        __syncthreads();

        // ---- fragments + MFMA ----
        s16x8 af[FM], bfr[FN];
#pragma unroll
        for (int mi = 0; mi < FM; ++mi) {
            int r = wr * (BM / 2) + mi * 16 + l15;
            af[mi] = *(const s16x8*)&As[r * ROWU + g * 8];
        }
#pragma unroll
        for (int ni = 0; ni < FN; ++ni) {
            int c = wc * (BN / 2) + ni * 16 + l15;
            bfr[ni] = *(const s16x8*)&Bs[c * ROWU + g * 8];
        }
#pragma unroll
        for (int mi = 0; mi < FM; ++mi)
#pragma unroll
            for (int ni = 0; ni < FN; ++ni)
                acc[mi][ni] = __builtin_amdgcn_mfma_f32_16x16x32_bf16(
                    af[mi], bfr[ni], acc[mi][ni], 0, 0, 0);
        __syncthreads();
    }

    // ---- epilogue: bias (+res) (relu) -> f32 ws or dtype out ----
    float* cfz = Cf ? (Cf + (size_t)z * sO) : nullptr;
#pragma unroll
    for (int mi = 0; mi < FM; ++mi) {
#pragma unroll
        for (int ni = 0; ni < FN; ++ni) {
            int n = col0 + wc * (BN / 2) + ni * 16 + l15;
            float bv = ldw(bias, b_off + (size_t)z * sB + n, isbf);
#pragma unroll
            for (int q = 0; q < 4; ++q) {
                int m = row0 + wr * (BM / 2) + mi * 16 + g * 4 + q;
                float v = acc[mi][ni][q] + bv;
                size_t oidx = (size_t)m * N + n;
                if (res)  v += res[oidx];
                if (relu) v = fmaxf(v, 0.f);
                if (Cout) {
                    if (isbf) ((bf16*)Cout)[oidx] = __float2bfloat16(v);
                    else      ((float*)Cout)[oidx] = v;
                } else {
                    cfz[oidx] = v;
                }
            }
        }
    }
}

// ---------------------------------------------------------------------------
// Flash attention (MFMA bf16). Grid (S/64, H, B), 256 threads = 4 waves.
// Block handles 64 q-rows of one (b,h); wave w owns q-rows w*16..w*16+15.
// K-tile loop (64 kv rows): stage K[kv][64] bf16, Vt[d][kv] bf16 in LDS;
// QK^T and PV via mfma_f32_16x16x32_bf16 with the verified frag pattern:
//   A,B frags read row-major [row][k]: row=lane&15, k=(lane>>4)*8+j;
//   C/D: col=lane&15, row=(lane>>4)*4+reg.
// Online softmax per 16-lane group (shfl_xor 1/2/4/8). P goes through LDS
// (same-wave DS ordering -> no barrier) to become the PV A-operand.
// Scale 1/8 folded into Q bf16 convert (exact). Causal skips tiles past diag.
// ---------------------------------------------------------------------------
#define QBLK_ 64
#define KVB_  64
#define LROW_ 72

template<int CAUSAL>
__global__ __launch_bounds__(256)
void fattn_kernel(const float* __restrict__ Q, const float* __restrict__ Kp,
                  const float* __restrict__ Vp, float* __restrict__ O)
{
    __shared__ __align__(16) unsigned short Ks[64 * LROW_];
    __shared__ __align__(16) unsigned short Vt[64 * LROW_];
    __shared__ __align__(16) unsigned short QP[64 * LROW_];  // Q, then P

    const int q0  = blockIdx.x * QBLK_;
    const int h   = blockIdx.y, b = blockIdx.z;
    const int tid = threadIdx.x;
    const int lane = tid & 63, w = tid >> 6;
    const int l15 = lane & 15, g = lane >> 4;

    // ---- stage Q (scaled by 1/8, exact in bf16) ----
    {
        int r = tid >> 2, c = (tid & 3) * 16;
        const float* qp = Q + ((size_t)(b * S_ + q0 + r) * H_ + h) * DK_ + c;
        u16x8 v0, v1;
#pragma unroll
        for (int j = 0; j < 8; ++j) v0[j] = f2b(qp[j] * 0.125f);
#pragma unroll
        for (int j = 0; j < 8; ++j) v1[j] = f2b(qp[8 + j] * 0.125f);
        *(u16x8*)&QP[r * LROW_ + c]     = v0;
        *(u16x8*)&QP[r * LROW_ + c + 8] = v1;
    }
    __syncthreads();
    s16x8 aq0 = *(const s16x8*)&QP[(w * 16 + l15) * LROW_ + g * 8];
    s16x8 aq1 = *(const s16x8*)&QP[(w * 16 + l15) * LROW_ + 32 + g * 8];

    float m[4] = {-INFINITY, -INFINITY, -INFINITY, -INFINITY};
    float l[4] = {0.f, 0.f, 0.f, 0.f};
    f32x4 o[4];
#pragma unroll
    for (int ni = 0; ni < 4; ++ni) o[ni] = (f32x4){0.f, 0.f, 0.f, 0.f};

    const int nt = CAUSAL ? (q0 / KVB_ + 1) : (S_ / KVB_);
    for (int t = 0; t < nt; ++t) {
        const int j0 = t * KVB_;
        // ---- stage K tile: Ks[kv][d] bf16 ----
        {
            int r = tid >> 2, c = (tid & 3) * 16;
            const float* kp = Kp + ((size_t)(b * S_ + j0 + r) * H_ + h) * DK_ + c;
            u16x8 v0, v1;
#pragma unroll
            for (int j = 0; j < 8; ++j) v0[j] = f2b(kp[j]);
#pragma unroll
            for (int j = 0; j < 8; ++j) v1[j] = f2b(kp[8 + j]);
            *(u16x8*)&Ks[r * LROW_ + c]     = v0;
            *(u16x8*)&Ks[r * LROW_ + c + 8] = v1;
        }
        // ---- stage V transposed: Vt[d][kv] bf16 (coalesced global reads) ----
        {
            int d = tid & 63, kq = tid >> 6;
            const float* vp = Vp + ((size_t)(b * S_ + j0 + kq * 16) * H_ + h) * DK_ + d;
            u16x8 v0, v1;
#pragma unroll
            for (int j = 0; j < 8; ++j) v0[j] = f2b(vp[(size_t)j * (H_ * DK_)]);
#pragma unroll
            for (int j = 0; j < 8; ++j) v1[j] = f2b(vp[(size_t)(8 + j) * (H_ * DK_)]);
            *(u16x8*)&Vt[d * LROW_ + kq * 16]     = v0;
            *(u16x8*)&Vt[d * LROW_ + kq * 16 + 8] = v1;
        }
        __syncthreads();

        // ---- QK^T: 16 q x 64 kv per wave ----
        f32x4 sc[4];
#pragma unroll
        for (int ni = 0; ni < 4; ++ni) {
            s16x8 bk0 = *(const s16x8*)&Ks[(ni * 16 + l15) * LROW_ + g * 8];
            s16x8 bk1 = *(const s16x8*)&Ks[(ni * 16 + l15) * LROW_ + 32 + g * 8];
            f32x4 a = (f32x4){0.f, 0.f, 0.f, 0.f};
            a = __builtin_amdgcn_mfma_f32_16x16x32_bf16(aq0, bk0, a, 0, 0, 0);
            a = __builtin_amdgcn_mfma_f32_16x16x32_bf16(aq1, bk1, a, 0, 0, 0);
            sc[ni] = a;
        }
        // ---- causal mask (diagonal tile only) ----
        if (CAUSAL && (j0 + KVB_ > q0)) {
#pragma unroll
            for (int ni = 0; ni < 4; ++ni)
#pragma unroll
                for (int r = 0; r < 4; ++r) {
                    int qrow = q0 + w * 16 + g * 4 + r;
                    int col  = j0 + ni * 16 + l15;
                    if (col > qrow) sc[ni][r] = -INFINITY;
                }
        }
        // ---- online softmax (per 16-lane group rows) ----
        float pr[4][4];
#pragma unroll
        for (int r = 0; r < 4; ++r) {
            float mt = fmaxf(fmaxf(sc[0][r], sc[1][r]), fmaxf(sc[2][r], sc[3][r]));
#pragma unroll
            for (int sft = 1; sft < 16; sft <<= 1)
                mt = fmaxf(mt, __shfl_xor(mt, sft, 64));
            float mn = fmaxf(m[r], mt);
            float rescale = __expf(m[r] - mn);   // t=0: exp(-inf)=0
            float rs = 0.f;
#pragma unroll
            for (int ni = 0; ni < 4; ++ni) {
                float p = __expf(sc[ni][r] - mn);
                pr[ni][r] = p;
                rs += p;
            }
#pragma unroll
            for (int sft = 1; sft < 16; sft <<= 1)
                rs += __shfl_xor(rs, sft, 64);
            l[r] = l[r] * rescale + rs;
            m[r] = mn;
#pragma unroll
            for (int ni = 0; ni < 4; ++ni) o[ni][r] *= rescale;
        }
        // ---- P -> LDS (per-wave rows; same-wave DS order, no barrier) ----
#pragma unroll
        for (int ni = 0; ni < 4; ++ni)
#pragma unroll
            for (int r = 0; r < 4; ++r)
                QP[(w * 16 + g * 4 + r) * LROW_ + ni * 16 + l15] = f2b(pr[ni][r]);
        // ---- PV: o[q][d] += P[q][kv] * V[kv][d] ----
        s16x8 pa0 = *(const s16x8*)&QP[(w * 16 + l15) * LROW_ + g * 8];
        s16x8 pa1 = *(const s16x8*)&QP[(w * 16 + l15) * LROW_ + 32 + g * 8];
#pragma unroll
        for (int ni = 0; ni < 4; ++ni) {
            s16x8 vb0 = *(const s16x8*)&Vt[(ni * 16 + l15) * LROW_ + g * 8];
            s16x8 vb1 = *(const s16x8*)&Vt[(ni * 16 + l15) * LROW_ + 32 + g * 8];
            o[ni] = __builtin_amdgcn_mfma_f32_16x16x32_bf16(pa0, vb0, o[ni], 0, 0, 0);
            o[ni] = __builtin_amdgcn_mfma_f32_16x16x32_bf16(pa1, vb1, o[ni], 0, 0, 0);
        }
        __syncthreads();
    }

    // ---- epilogue: O = o / l ----
#pragma unroll
    for (int r = 0; r < 4; ++r) {
        float inv = 1.0f / l[r];
        int qrow = q0 + w * 16 + g * 4 + r;
        float* op = O + ((size_t)(b * S_ + qrow) * H_ + h) * DK_;
#pragma unroll
        for (int ni = 0; ni < 4; ++ni)
            op[ni * 16 + l15] = o[ni][r] * inv;
    }
}

// ---------------------------------------------------------------------------
// LayerNorm over rows of 512. One block per row. eps = 1e-5.
// ---------------------------------------------------------------------------
__global__ __launch_bounds__(256)
void layernorm_kernel(const float* __restrict__ X,
                      const void* __restrict__ g, size_t g_off,
                      const void* __restrict__ bb, size_t b_off,
                      float* __restrict__ Y, const int* __restrict__ flagp)
{
    __shared__ float red[256];
    const int isbf = *flagp;
    const int row = blockIdx.x, tid = threadIdx.x;
    const float* x = X + (size_t)row * D_;
    float v0 = x[tid], v1 = x[tid + 256];
    red[tid] = v0 + v1;
    __syncthreads();
    for (int s = 128; s > 0; s >>= 1) {
        if (tid < s) red[tid] += red[tid + s];
        __syncthreads();
    }
    float mean = red[0] * (1.0f / (float)D_);
    __syncthreads();
    float d0 = v0 - mean, d1 = v1 - mean;
    red[tid] = d0 * d0 + d1 * d1;
    __syncthreads();
    for (int s = 128; s > 0; s >>= 1) {
        if (tid < s) red[tid] += red[tid + s];
        __syncthreads();
    }
    float r = rsqrtf(red[0] * (1.0f / (float)D_) + 1e-5f);
    float* y = Y + (size_t)row * D_;
    y[tid]       = ldw(g, g_off + tid, isbf)       * d0 * r + ldw(bb, b_off + tid, isbf);
    y[tid + 256] = ldw(g, g_off + tid + 256, isbf) * d1 * r + ldw(bb, b_off + tid + 256, isbf);
}

// ---------------------------------------------------------------------------
extern "C" void kernel_launch(void* const* d_in, const int* in_sizes, int n_in,
                              void* d_out, int out_size, void* d_ws, size_t ws_size,
                              hipStream_t stream)
{
    (void)in_sizes; (void)n_in; (void)out_size;

    const int*  src      = (const int*)d_in[0];
    const int*  tgt      = (const int*)d_in[1];
    // d_in[2] = tgt_mask: deterministic causal triu -> recomputed, never read
    const void* src_emb  = d_in[3];
    const void* tgt_emb  = d_in[4];
    const void* eaw      = d_in[5];   // [L,4,D,D]
    const void* eab      = d_in[6];   // [L,4,D]
    const void* ew1      = d_in[7];   // [L,D,DFF]
    const void* eb1      = d_in[8];   // [L,DFF]
    const void* ew2      = d_in[9];   // [L,DFF,D]
    const void* eb2      = d_in[10];  // [L,D]
    const void* elg      = d_in[11];  // [L,2,D]
    const void* elb      = d_in[12];  // [L,2,D]
    const void* daw      = d_in[13];  // [L,8,D,D]
    const void* dab      = d_in[14];  // [L,8,D]
    const void* dw1      = d_in[15];
    const void* db1      = d_in[16];
    const void* dw2      = d_in[17];
    const void* db2      = d_in[18];
    const void* dlg      = d_in[19];  // [L,3,D]
    const void* dlb      = d_in[20];  // [L,3,D]
    const void* gen_w    = d_in[21];  // [D,V]
    const void* gen_b    = d_in[22];  // [V]

    // workspace carve-up (unchanged: 84 MB)
    const size_t tokD = (size_t)NT_ * D_;          // 2,097,152
    const size_t tokF = (size_t)NT_ * DFF_;        // 8,388,608
    const size_t need = 256 + (6 * tokD + tokF) * sizeof(float);
    if (ws_size < need) return;                    // visible failure, no OOB

    int*   flagp = (int*)d_ws;
    float* xbuf = (float*)((char*)d_ws + 256);     // encoder state
    float* ybuf = xbuf + tokD;         // decoder state
    float* qbuf = ybuf + tokD;         // q proj / pre-LN tmp (stride base for z)
    float* kbuf = qbuf + tokD;
    float* vbuf = kbuf + tokD;
    float* abuf = vbuf + tokD;         // attention output
    float* fbuf = abuf + tokD;         // ffn mid [NT, DFF]
    float* tbuf = qbuf;                // pre-LN tmp (q dead by then)

    detect_kernel<<<1, 1, 0, stream>>>(elg, flagp);

    auto g64 = [&](const float* A, const void* W, size_t w_off,
                   const void* bias, size_t b_off, const float* res,
                   float* Cf, void* Cout, int M, int N, int K, int relu,
                   int nz, size_t sW, size_t sO, size_t sB) {
        dim3 grid(N / 128, M / 64, nz);
        gemm_mfma_kernel<64, 128><<<grid, 256, 0, stream>>>(
            A, W, w_off, bias, b_off, res, Cf, Cout, M, N, K, relu, sW, sO, sB, flagp);
    };
    auto g128 = [&](const float* A, const void* W, size_t w_off,
                    const void* bias, size_t b_off, const float* res,
                    float* Cf, void* Cout, int M, int N, int K, int relu,
                    int nz, size_t sW, size_t sO, size_t sB) {
        dim3 grid(N / 128, M / 128, nz);
        gemm_mfma_kernel<128, 128><<<grid, 256, 0, stream>>>(
            A, W, w_off, bias, b_off, res, Cf, Cout, M, N, K, relu, sW, sO, sB, flagp);
    };
    auto attn = [&](const float* Q, const float* Kp, const float* Vp,
                    float* O, int causal) {
        dim3 g(S_ / QBLK_, H_, B_);
        if (causal)
            fattn_kernel<1><<<g, 256, 0, stream>>>(Q, Kp, Vp, O);
        else
            fattn_kernel<0><<<g, 256, 0, stream>>>(Q, Kp, Vp, O);
    };
    auto ln = [&](const float* X, const void* g_, size_t g_off,
                  const void* b_, size_t b_off, float* Y) {
        layernorm_kernel<<<NT_, 256, 0, stream>>>(X, g_, g_off, b_, b_off, Y, flagp);
    };

    // ---- embeddings ----
    embed_kernel<<<(NT_ * D_) / 256, 256, 0, stream>>>(src, src_emb, xbuf, flagp);
    embed_kernel<<<(NT_ * D_) / 256, 256, 0, stream>>>(tgt, tgt_emb, ybuf, flagp);

    const size_t DD = (size_t)D_ * D_;

    // ---- encoder ----
    for (int i = 0; i < L_; ++i) {
        size_t w0 = (size_t)i * 4 * DD;
        size_t b0 = (size_t)i * 4 * D_;
        // fused QKV: z = 0,1,2 -> qbuf,kbuf,vbuf
        g64(xbuf, eaw, w0, eab, b0, nullptr, qbuf, nullptr, NT_, D_, D_, 0,
            3, DD, tokD, D_);
        attn(qbuf, kbuf, vbuf, abuf, 0);
        g64(abuf, eaw, w0 + 3 * DD, eab, b0 + 3 * D_, xbuf, tbuf, nullptr,
            NT_, D_, D_, 0, 1, 0, 0, 0);
        ln(tbuf, elg, (size_t)(i * 2 + 0) * D_, elb, (size_t)(i * 2 + 0) * D_, xbuf);
        g128(xbuf, ew1, (size_t)i * D_ * DFF_, eb1, (size_t)i * DFF_, nullptr,
             fbuf, nullptr, NT_, DFF_, D_, 1, 1, 0, 0, 0);
        g64(fbuf, ew2, (size_t)i * DFF_ * D_, eb2, (size_t)i * D_, xbuf,
            tbuf, nullptr, NT_, D_, DFF_, 0, 1, 0, 0, 0);
        ln(tbuf, elg, (size_t)(i * 2 + 1) * D_, elb, (size_t)(i * 2 + 1) * D_, xbuf);
    }

    // ---- decoder ----
    for (int i = 0; i < L_; ++i) {
        size_t w0 = (size_t)i * 8 * DD;
        size_t b0 = (size_t)i * 8 * D_;
        // masked self-attention (fused QKV)
        g64(ybuf, daw, w0, dab, b0, nullptr, qbuf, nullptr, NT_, D_, D_, 0,
            3, DD, tokD, D_);
        attn(qbuf, kbuf, vbuf, abuf, 1);
        g64(abuf, daw, w0 + 3 * DD, dab, b0 + 3 * D_, ybuf, tbuf, nullptr,
            NT_, D_, D_, 0, 1, 0, 0, 0);
        ln(tbuf, dlg, (size_t)(i * 3 + 0) * D_, dlb, (size_t)(i * 3 + 0) * D_, ybuf);
        // cross-attention: q from y; fused K,V from encoder output x
        g64(ybuf, daw, w0 + 4 * DD, dab, b0 + 4 * D_, nullptr, qbuf, nullptr,
            NT_, D_, D_, 0, 1, 0, 0, 0);
        g64(xbuf, daw, w0 + 5 * DD, dab, b0 + 5 * D_, nullptr, kbuf, nullptr,
            NT_, D_, D_, 0, 2, DD, tokD, D_);
        attn(qbuf, kbuf, vbuf, abuf, 0);
        g64(abuf, daw, w0 + 7 * DD, dab, b0 + 7 * D_, ybuf, tbuf, nullptr,
            NT_, D_, D_, 0, 1, 0, 0, 0);
        ln(tbuf, dlg, (size_t)(i * 3 + 1) * D_, dlb, (size_t)(i * 3 + 1) * D_, ybuf);
        // FFN
        g128(ybuf, dw1, (size_t)i * D_ * DFF_, db1, (size_t)i * DFF_, nullptr,
             fbuf, nullptr, NT_, DFF_, D_, 1, 1, 0, 0, 0);
        g64(fbuf, dw2, (size_t)i * DFF_ * D_, db2, (size_t)i * D_, ybuf,
            tbuf, nullptr, NT_, D_, DFF_, 0, 1, 0, 0, 0);
        ln(tbuf, dlg, (size_t)(i * 3 + 2) * D_, dlb, (size_t)(i * 3 + 2) * D_, ybuf);
    }

    // ---- generator -> d_out (dtype per flag); V=16000 = 125*128 ----
    g128(ybuf, gen_w, 0, gen_b, 0, nullptr, nullptr, d_out, NT_, V_, D_, 0,
         1, 0, 0, 0);
}

// Round 4
// 3239.442 us; speedup vs baseline: 6.8923x; 1.7717x over previous
//
#include <hip/hip_runtime.h>
#include <hip/hip_bf16.h>
#include <math.h>

typedef __hip_bfloat16 bf16;
typedef __attribute__((ext_vector_type(8))) short          s16x8;   // MFMA a/b frag (8 bf16)
typedef __attribute__((ext_vector_type(8))) unsigned short u16x8;
typedef __attribute__((ext_vector_type(4))) float          f32x4;   // MFMA acc

#define B_   4
#define S_   1024
#define D_   512
#define H_   8
#define DK_  64
#define DFF_ 2048
#define L_   6
#define V_   16000
#define NT_  (B_ * S_)   // 4096 tokens

// Runtime dtype flag: 1 if float tensors are bf16 on device, 0 if f32.
__global__ void detect_kernel(const void* __restrict__ g, int* __restrict__ flag)
{
    const unsigned short* u = (const unsigned short*)g;
    *flag = (u[0] == 0x3F80 && u[1] == 0x3F80) ? 1 : 0;
}

__device__ __forceinline__ float ldw(const void* p, size_t i, int isbf)
{
    if (isbf) return __bfloat162float(((const bf16*)p)[i]);
    return ((const float*)p)[i];
}

// f32 -> bf16 bits, round-to-nearest-even
__device__ __forceinline__ unsigned short f2b(float f)
{
    unsigned int u = __float_as_uint(f);
    return (unsigned short)((u + 0x7FFFu + ((u >> 16) & 1u)) >> 16);
}
__device__ __forceinline__ float b2f(unsigned short u)
{
    return __uint_as_float((unsigned int)u << 16);
}

// ---------------------------------------------------------------------------
// Embedding + positional encoding: X[bs,d] = emb[tok[bs]][d] + pe(s,d)
// ---------------------------------------------------------------------------
__global__ __launch_bounds__(256)
void embed_kernel(const int* __restrict__ tok, const void* __restrict__ emb,
                  float* __restrict__ X, const int* __restrict__ flagp)
{
    const int isbf = *flagp;
    int idx = blockIdx.x * 256 + threadIdx.x;
    int d  = idx & (D_ - 1);
    int bs = idx >> 9;
    int s  = bs & (S_ - 1);
    int t  = tok[bs];
    float e = ldw(emb, (size_t)t * D_ + d, isbf);
    float expo = (float)(d & ~1) * (1.0f / (float)D_);
    float div  = powf(10000.0f, expo);
    float arg  = (float)s / div;
    float pe   = (d & 1) ? cosf(arg) : sinf(arg);
    X[idx] = e + pe;
}

// ---------------------------------------------------------------------------
// Weight preconvert + transpose: W[z][K][N] (flag dtype) -> Wt[z][N][K] bf16.
// 64x64 tile via LDS. One-time per launch; makes GEMM B-staging coalesced
// u16x8 loads with zero converts.
// ---------------------------------------------------------------------------
__global__ __launch_bounds__(256)
void wconv_kernel(const void* __restrict__ W, unsigned short* __restrict__ Wt,
                  int K, int N, const int* __restrict__ flagp)
{
    __shared__ unsigned short T[64 * 72];
    const int isbf = *flagp;
    const int tid = threadIdx.x;
    const int n0 = blockIdx.x * 64, k0 = blockIdx.y * 64;
    const size_t mb = (size_t)blockIdx.z * K * N;
#pragma unroll
    for (int i = 0; i < 16; ++i) {
        int idx = i * 256 + tid;
        int kk = idx >> 6, n = idx & 63;
        unsigned short v;
        if (isbf) v = ((const unsigned short*)W)[mb + (size_t)(k0 + kk) * N + n0 + n];
        else      v = f2b(((const float*)W)[mb + (size_t)(k0 + kk) * N + n0 + n]);
        T[n * 72 + kk] = v;
    }
    __syncthreads();
#pragma unroll
    for (int j = 0; j < 2; ++j) {
        int unit = j * 256 + tid;
        int n = unit >> 3, q = unit & 7;
        *(u16x8*)&Wt[mb + (size_t)(n0 + n) * K + k0 + q * 8] =
            *(const u16x8*)&T[n * 72 + q * 8];
    }
}

// ---------------------------------------------------------------------------
// MFMA GEMM v2: C[M,N] = A[M,K] * W + bias [+res f32] [relu]
//   ABF: A is bf16 ws (1) or f32 (0, reg-converted)
//   WT : B from pre-transposed bf16 Wt[n][k] (1) or original W[k][n] (0)
//   OB : 0 = f32 out (C), 1 = bf16 out (C), 2 = d_out runtime dtype (Cout)
//   256 thr = 4 waves 2x2; BK=32; LDS rows padded to 40 ushorts.
//   Frags: A,B read row-major [row][k]: row=lane&15, k=(lane>>4)*8+j;
//   C/D: col=lane&15, row=(lane>>4)*4+reg.  blockIdx.z batches weights.
// ---------------------------------------------------------------------------
template<int BM, int BN, int ABF, int WT, int OB>
__global__ __launch_bounds__(256)
void gemm2_kernel(const void* __restrict__ A,
                  const void* __restrict__ W, size_t w_off,
                  const void* __restrict__ bias, size_t b_off,
                  const float* __restrict__ res,
                  void* __restrict__ C, void* __restrict__ Cout,
                  int M, int N, int K, int relu,
                  size_t sW, size_t sO, size_t sB,
                  const int* __restrict__ flagp)
{
    constexpr int ROWU = 40;
    constexpr int FM = BM / 32;
    constexpr int FN = BN / 32;
    __shared__ __align__(16) unsigned short As[BM * ROWU];
    __shared__ __align__(16) unsigned short Bs[BN * ROWU];

    const int isbf = *flagp;
    const int tid  = threadIdx.x;
    const int lane = tid & 63;
    const int wid  = tid >> 6;
    const int wr   = wid >> 1, wc = wid & 1;
    const int l15  = lane & 15, g = lane >> 4;
    const int row0 = blockIdx.y * BM;
    const int col0 = blockIdx.x * BN;
    const int z    = blockIdx.z;
    const size_t wbase = w_off + (size_t)z * sW;

    f32x4 acc[FM][FN];
#pragma unroll
    for (int i = 0; i < FM; ++i)
#pragma unroll
        for (int j = 0; j < FN; ++j)
            acc[i][j] = (f32x4){0.f, 0.f, 0.f, 0.f};

    for (int k0 = 0; k0 < K; k0 += 32) {
        // ---- stage A ----
        if (ABF) {
#pragma unroll
            for (int u = 0; u < BM / 64; ++u) {
                int unit = tid + u * 256;
                int r = unit >> 2, q = unit & 3;
                *(u16x8*)&As[r * ROWU + q * 8] = *(const u16x8*)
                    ((const unsigned short*)A + (size_t)(row0 + r) * K + k0 + q * 8);
            }
        } else {
#pragma unroll
            for (int u = 0; u < (BM * 4) / 256; ++u) {
                int unit = tid + u * 256;
                int r = unit >> 2, q = unit & 3;
                const float* ap = (const float*)A + (size_t)(row0 + r) * K + k0 + q * 8;
                float4 f0 = *(const float4*)ap;
                float4 f1 = *(const float4*)(ap + 4);
                u16x8 v;
                v[0] = f2b(f0.x); v[1] = f2b(f0.y); v[2] = f2b(f0.z); v[3] = f2b(f0.w);
                v[4] = f2b(f1.x); v[5] = f2b(f1.y); v[6] = f2b(f1.z); v[7] = f2b(f1.w);
                *(u16x8*)&As[r * ROWU + q * 8] = v;
            }
        }
        // ---- stage B ----
        if (WT) {
#pragma unroll
            for (int u = 0; u < BN / 64; ++u) {
                int unit = tid + u * 256;
                int n = unit >> 2, q = unit & 3;
                *(u16x8*)&Bs[n * ROWU + q * 8] = *(const u16x8*)
                    ((const unsigned short*)W + wbase + (size_t)(col0 + n) * K + k0 + q * 8);
            }
        } else {
#pragma unroll
            for (int u = 0; u < (BN * 4) / 256; ++u) {
                int unit = tid + u * 256;
                int n = unit >> 2, q = unit & 3;
                u16x8 v;
                if (isbf) {
                    const unsigned short* wp = (const unsigned short*)W;
#pragma unroll
                    for (int j = 0; j < 8; ++j)
                        v[j] = wp[wbase + (size_t)(k0 + q * 8 + j) * N + col0 + n];
                } else {
                    const float* wp = (const float*)W;
#pragma unroll
                    for (int j = 0; j < 8; ++j)
                        v[j] = f2b(wp[wbase + (size_t)(k0 + q * 8 + j) * N + col0 + n]);
                }
                *(u16x8*)&Bs[n * ROWU + q * 8] = v;
            }
        }
        __syncthreads();

        // ---- fragments + MFMA ----
        s16x8 af[FM], bfr[FN];
#pragma unroll
        for (int mi = 0; mi < FM; ++mi) {
            int r = wr * (BM / 2) + mi * 16 + l15;
            af[mi] = *(const s16x8*)&As[r * ROWU + g * 8];
        }
#pragma unroll
        for (int ni = 0; ni < FN; ++ni) {
            int c = wc * (BN / 2) + ni * 16 + l15;
            bfr[ni] = *(const s16x8*)&Bs[c * ROWU + g * 8];
        }
#pragma unroll
        for (int mi = 0; mi < FM; ++mi)
#pragma unroll
            for (int ni = 0; ni < FN; ++ni)
                acc[mi][ni] = __builtin_amdgcn_mfma_f32_16x16x32_bf16(
                    af[mi], bfr[ni], acc[mi][ni], 0, 0, 0);
        __syncthreads();
    }

    // ---- epilogue ----
#pragma unroll
    for (int mi = 0; mi < FM; ++mi) {
#pragma unroll
        for (int ni = 0; ni < FN; ++ni) {
            int n = col0 + wc * (BN / 2) + ni * 16 + l15;
            float bv = ldw(bias, b_off + (size_t)z * sB + n, isbf);
#pragma unroll
            for (int q = 0; q < 4; ++q) {
                int m = row0 + wr * (BM / 2) + mi * 16 + g * 4 + q;
                float v = acc[mi][ni][q] + bv;
                size_t oidx = (size_t)m * N + n;
                if (res)  v += res[oidx];
                if (relu) v = fmaxf(v, 0.f);
                if (OB == 0)      ((float*)C + (size_t)z * sO)[oidx] = v;
                else if (OB == 1) ((unsigned short*)C + (size_t)z * sO)[oidx] = f2b(v);
                else {
                    if (isbf) ((bf16*)Cout)[oidx] = __float2bfloat16(v);
                    else      ((float*)Cout)[oidx] = v;
                }
            }
        }
    }
}

// ---------------------------------------------------------------------------
// Flash attention (MFMA bf16). Q/K/V/O are bf16 [B,S,H,DK] workspace streams.
// Grid (S/64, H, B), 256 thr = 4 waves; wave w owns q-rows w*16..w*16+15.
// Scale 1/8 folded into Q staging (exact). Online softmax per 16-lane group.
// ---------------------------------------------------------------------------
#define QBLK_ 64
#define KVB_  64
#define LROW_ 72

template<int CAUSAL>
__global__ __launch_bounds__(256)
void fattn_kernel(const unsigned short* __restrict__ Q,
                  const unsigned short* __restrict__ Kp,
                  const unsigned short* __restrict__ Vp,
                  unsigned short* __restrict__ O)
{
    __shared__ __align__(16) unsigned short Ks[64 * LROW_];
    __shared__ __align__(16) unsigned short Vt[64 * LROW_];
    __shared__ __align__(16) unsigned short QP[64 * LROW_];  // Q, then P

    const int q0  = blockIdx.x * QBLK_;
    const int h   = blockIdx.y, b = blockIdx.z;
    const int tid = threadIdx.x;
    const int lane = tid & 63, w = tid >> 6;
    const int l15 = lane & 15, g = lane >> 4;

    // ---- stage Q (scaled by 1/8, exact) ----
    {
        int r = tid >> 2, c = (tid & 3) * 16;
        const unsigned short* qp = Q + ((size_t)(b * S_ + q0 + r) * H_ + h) * DK_ + c;
        u16x8 v0 = *(const u16x8*)qp, v1 = *(const u16x8*)(qp + 8);
#pragma unroll
        for (int j = 0; j < 8; ++j) v0[j] = f2b(b2f(v0[j]) * 0.125f);
#pragma unroll
        for (int j = 0; j < 8; ++j) v1[j] = f2b(b2f(v1[j]) * 0.125f);
        *(u16x8*)&QP[r * LROW_ + c]     = v0;
        *(u16x8*)&QP[r * LROW_ + c + 8] = v1;
    }
    __syncthreads();
    s16x8 aq0 = *(const s16x8*)&QP[(w * 16 + l15) * LROW_ + g * 8];
    s16x8 aq1 = *(const s16x8*)&QP[(w * 16 + l15) * LROW_ + 32 + g * 8];

    float m[4] = {-INFINITY, -INFINITY, -INFINITY, -INFINITY};
    float l[4] = {0.f, 0.f, 0.f, 0.f};
    f32x4 o[4];
#pragma unroll
    for (int ni = 0; ni < 4; ++ni) o[ni] = (f32x4){0.f, 0.f, 0.f, 0.f};

    const int nt = CAUSAL ? (q0 / KVB_ + 1) : (S_ / KVB_);
    for (int t = 0; t < nt; ++t) {
        const int j0 = t * KVB_;
        // ---- stage K tile: Ks[kv][d] (straight bf16 copy) ----
        {
            int r = tid >> 2, c = (tid & 3) * 16;
            const unsigned short* kp = Kp + ((size_t)(b * S_ + j0 + r) * H_ + h) * DK_ + c;
            *(u16x8*)&Ks[r * LROW_ + c]     = *(const u16x8*)kp;
            *(u16x8*)&Ks[r * LROW_ + c + 8] = *(const u16x8*)(kp + 8);
        }
        // ---- stage V transposed: Vt[d][kv] ----
        {
            int d = tid & 63, kq = tid >> 6;
            const unsigned short* vp = Vp + ((size_t)(b * S_ + j0 + kq * 16) * H_ + h) * DK_ + d;
            u16x8 v0, v1;
#pragma unroll
            for (int j = 0; j < 8; ++j) v0[j] = vp[(size_t)j * (H_ * DK_)];
#pragma unroll
            for (int j = 0; j < 8; ++j) v1[j] = vp[(size_t)(8 + j) * (H_ * DK_)];
            *(u16x8*)&Vt[d * LROW_ + kq * 16]     = v0;
            *(u16x8*)&Vt[d * LROW_ + kq * 16 + 8] = v1;
        }
        __syncthreads();

        // ---- QK^T: 16 q x 64 kv per wave ----
        f32x4 sc[4];
#pragma unroll
        for (int ni = 0; ni < 4; ++ni) {
            s16x8 bk0 = *(const s16x8*)&Ks[(ni * 16 + l15) * LROW_ + g * 8];
            s16x8 bk1 = *(const s16x8*)&Ks[(ni * 16 + l15) * LROW_ + 32 + g * 8];
            f32x4 a = (f32x4){0.f, 0.f, 0.f, 0.f};
            a = __builtin_amdgcn_mfma_f32_16x16x32_bf16(aq0, bk0, a, 0, 0, 0);
            a = __builtin_amdgcn_mfma_f32_16x16x32_bf16(aq1, bk1, a, 0, 0, 0);
            sc[ni] = a;
        }
        if (CAUSAL && (j0 + KVB_ > q0)) {
#pragma unroll
            for (int ni = 0; ni < 4; ++ni)
#pragma unroll
                for (int r = 0; r < 4; ++r) {
                    int qrow = q0 + w * 16 + g * 4 + r;
                    int col  = j0 + ni * 16 + l15;
                    if (col > qrow) sc[ni][r] = -INFINITY;
                }
        }
        // ---- online softmax ----
        float pr[4][4];
#pragma unroll
        for (int r = 0; r < 4; ++r) {
            float mt = fmaxf(fmaxf(sc[0][r], sc[1][r]), fmaxf(sc[2][r], sc[3][r]));
#pragma unroll
            for (int sft = 1; sft < 16; sft <<= 1)
                mt = fmaxf(mt, __shfl_xor(mt, sft, 64));
            float mn = fmaxf(m[r], mt);
            float rescale = __expf(m[r] - mn);
            float rs = 0.f;
#pragma unroll
            for (int ni = 0; ni < 4; ++ni) {
                float p = __expf(sc[ni][r] - mn);
                pr[ni][r] = p;
                rs += p;
            }
#pragma unroll
            for (int sft = 1; sft < 16; sft <<= 1)
                rs += __shfl_xor(rs, sft, 64);
            l[r] = l[r] * rescale + rs;
            m[r] = mn;
#pragma unroll
            for (int ni = 0; ni < 4; ++ni) o[ni][r] *= rescale;
        }
        // ---- P -> LDS (same-wave rows, no barrier needed) ----
#pragma unroll
        for (int ni = 0; ni < 4; ++ni)
#pragma unroll
            for (int r = 0; r < 4; ++r)
                QP[(w * 16 + g * 4 + r) * LROW_ + ni * 16 + l15] = f2b(pr[ni][r]);
        // ---- PV ----
        s16x8 pa0 = *(const s16x8*)&QP[(w * 16 + l15) * LROW_ + g * 8];
        s16x8 pa1 = *(const s16x8*)&QP[(w * 16 + l15) * LROW_ + 32 + g * 8];
#pragma unroll
        for (int ni = 0; ni < 4; ++ni) {
            s16x8 vb0 = *(const s16x8*)&Vt[(ni * 16 + l15) * LROW_ + g * 8];
            s16x8 vb1 = *(const s16x8*)&Vt[(ni * 16 + l15) * LROW_ + 32 + g * 8];
            o[ni] = __builtin_amdgcn_mfma_f32_16x16x32_bf16(pa0, vb0, o[ni], 0, 0, 0);
            o[ni] = __builtin_amdgcn_mfma_f32_16x16x32_bf16(pa1, vb1, o[ni], 0, 0, 0);
        }
        __syncthreads();
    }

    // ---- epilogue: O = o / l (bf16) ----
#pragma unroll
    for (int r = 0; r < 4; ++r) {
        float inv = 1.0f / l[r];
        int qrow = q0 + w * 16 + g * 4 + r;
        unsigned short* op = O + ((size_t)(b * S_ + qrow) * H_ + h) * DK_;
#pragma unroll
        for (int ni = 0; ni < 4; ++ni)
            op[ni * 16 + l15] = f2b(o[ni][r] * inv);
    }
}

// ---------------------------------------------------------------------------
// LayerNorm over rows of 512 (f32 in/out). eps = 1e-5.
// ---------------------------------------------------------------------------
__global__ __launch_bounds__(256)
void layernorm_kernel(const float* __restrict__ X,
                      const void* __restrict__ g, size_t g_off,
                      const void* __restrict__ bb, size_t b_off,
                      float* __restrict__ Y, const int* __restrict__ flagp)
{
    __shared__ float red[256];
    const int isbf = *flagp;
    const int row = blockIdx.x, tid = threadIdx.x;
    const float* x = X + (size_t)row * D_;
    float v0 = x[tid], v1 = x[tid + 256];
    red[tid] = v0 + v1;
    __syncthreads();
    for (int s = 128; s > 0; s >>= 1) {
        if (tid < s) red[tid] += red[tid + s];
        __syncthreads();
    }
    float mean = red[0] * (1.0f / (float)D_);
    __syncthreads();
    float d0 = v0 - mean, d1 = v1 - mean;
    red[tid] = d0 * d0 + d1 * d1;
    __syncthreads();
    for (int s = 128; s > 0; s >>= 1) {
        if (tid < s) red[tid] += red[tid + s];
        __syncthreads();
    }
    float r = rsqrtf(red[0] * (1.0f / (float)D_) + 1e-5f);
    float* y = Y + (size_t)row * D_;
    y[tid]       = ldw(g, g_off + tid, isbf)       * d0 * r + ldw(bb, b_off + tid, isbf);
    y[tid + 256] = ldw(g, g_off + tid + 256, isbf) * d1 * r + ldw(bb, b_off + tid + 256, isbf);
}

// ---------------------------------------------------------------------------
extern "C" void kernel_launch(void* const* d_in, const int* in_sizes, int n_in,
                              void* d_out, int out_size, void* d_ws, size_t ws_size,
                              hipStream_t stream)
{
    (void)in_sizes; (void)n_in; (void)out_size;

    const int*  src      = (const int*)d_in[0];
    const int*  tgt      = (const int*)d_in[1];
    const void* src_emb  = d_in[3];
    const void* tgt_emb  = d_in[4];
    const void* eaw      = d_in[5];   // [L,4,D,D]
    const void* eab      = d_in[6];
    const void* ew1      = d_in[7];   // [L,D,DFF]
    const void* eb1      = d_in[8];
    const void* ew2      = d_in[9];   // [L,DFF,D]
    const void* eb2      = d_in[10];
    const void* elg      = d_in[11];
    const void* elb      = d_in[12];
    const void* daw      = d_in[13];  // [L,8,D,D]
    const void* dab      = d_in[14];
    const void* dw1      = d_in[15];
    const void* db1      = d_in[16];
    const void* dw2      = d_in[17];
    const void* db2      = d_in[18];
    const void* dlg      = d_in[19];
    const void* dlb      = d_in[20];
    const void* gen_w    = d_in[21];  // [D,V]
    const void* gen_b    = d_in[22];

    const size_t tokD = (size_t)NT_ * D_;          // 2,097,152
    const size_t tokF = (size_t)NT_ * DFF_;        // 8,388,608
    const size_t DD   = (size_t)D_ * D_;           // 262,144

    // Wt region layout (elems, per-matrix bases mirror original offsets)
    const size_t O_EAW = 0;
    const size_t O_EW1 = O_EAW + 24ULL * DD;
    const size_t O_EW2 = O_EW1 + 6ULL * D_ * DFF_;
    const size_t O_DAW = O_EW2 + 6ULL * DFF_ * D_;
    const size_t O_DW1 = O_DAW + 48ULL * DD;
    const size_t O_DW2 = O_DW1 + 6ULL * D_ * DFF_;
    const size_t O_GEN = O_DW2 + 6ULL * DFF_ * D_;
    const size_t WTELEMS = O_GEN + (size_t)D_ * V_;    // 52,232,192

    // workspace carve-up
    size_t off = 256;
    int*   flagp = (int*)d_ws;
    float* xbuf = (float*)((char*)d_ws + off); off += tokD * 4;
    float* ybuf = (float*)((char*)d_ws + off); off += tokD * 4;
    float* tbuf = (float*)((char*)d_ws + off); off += tokD * 4;
    unsigned short* qb = (unsigned short*)((char*)d_ws + off); off += tokD * 2;
    unsigned short* kb = (unsigned short*)((char*)d_ws + off); off += tokD * 2;
    unsigned short* vb = (unsigned short*)((char*)d_ws + off); off += tokD * 2;
    unsigned short* ab = (unsigned short*)((char*)d_ws + off); off += tokD * 2;
    unsigned short* fb = (unsigned short*)((char*)d_ws + off); off += tokF * 2;
    const size_t need_small = off;
    unsigned short* Wt = (unsigned short*)((char*)d_ws + off); off += WTELEMS * 2;
    const size_t need_big = off;

    if (ws_size < need_small) return;              // visible failure, no OOB
    const bool big = (ws_size >= need_big);

    detect_kernel<<<1, 1, 0, stream>>>(elg, flagp);

    // ---- one-time weight preconvert + transpose (big path) ----
    if (big) {
        auto wc = [&](const void* W, size_t dstoff, int K, int N, int z) {
            dim3 g(N / 64, K / 64, z);
            wconv_kernel<<<g, 256, 0, stream>>>(W, Wt + dstoff, K, N, flagp);
        };
        wc(eaw,   O_EAW, 512, 512,   24);
        wc(ew1,   O_EW1, 512, 2048,  6);
        wc(ew2,   O_EW2, 2048, 512,  6);
        wc(daw,   O_DAW, 512, 512,   48);
        wc(dw1,   O_DW1, 512, 2048,  6);
        wc(dw2,   O_DW2, 2048, 512,  6);
        wc(gen_w, O_GEN, 512, 16000, 1);
    }

    // ---- GEMM launchers (template combos; big -> WT=1 path) ----
    // proj: A f32, out bf16 ws (64x64 tile)
    auto gP = [&](const float* A, const void* Wf, size_t roff, size_t woff,
                  const void* bias, size_t boff, unsigned short* C,
                  int N, int K, int nz, size_t sW, size_t sO, size_t sB) {
        dim3 grid(N / 64, NT_ / 64, nz);
        if (big) gemm2_kernel<64, 64, 0, 1, 1><<<grid, 256, 0, stream>>>(
            A, Wt, roff + woff, bias, boff, nullptr, C, nullptr,
            NT_, N, K, 0, sW, sO, sB, flagp);
        else     gemm2_kernel<64, 64, 0, 0, 1><<<grid, 256, 0, stream>>>(
            A, Wf, woff, bias, boff, nullptr, C, nullptr,
            NT_, N, K, 0, sW, sO, sB, flagp);
    };
    // out-proj / FFN2: A bf16 ws, res f32, out f32 ws (64x64 tile)
    auto gO = [&](const unsigned short* A, const void* Wf, size_t roff, size_t woff,
                  const void* bias, size_t boff, const float* res, float* C,
                  int N, int K) {
        dim3 grid(N / 64, NT_ / 64, 1);
        if (big) gemm2_kernel<64, 64, 1, 1, 0><<<grid, 256, 0, stream>>>(
            A, Wt, roff + woff, bias, boff, res, C, nullptr,
            NT_, N, K, 0, 0, 0, 0, flagp);
        else     gemm2_kernel<64, 64, 1, 0, 0><<<grid, 256, 0, stream>>>(
            A, Wf, woff, bias, boff, res, C, nullptr,
            NT_, N, K, 0, 0, 0, 0, flagp);
    };
    // FFN1: A f32, relu, out bf16 ws (128x128 tile)
    auto gF1 = [&](const float* A, const void* Wf, size_t roff, size_t woff,
                   const void* bias, size_t boff, unsigned short* C) {
        dim3 grid(DFF_ / 128, NT_ / 128, 1);
        if (big) gemm2_kernel<128, 128, 0, 1, 1><<<grid, 256, 0, stream>>>(
            A, Wt, roff + woff, bias, boff, nullptr, C, nullptr,
            NT_, DFF_, D_, 1, 0, 0, 0, flagp);
        else     gemm2_kernel<128, 128, 0, 0, 1><<<grid, 256, 0, stream>>>(
            A, Wf, woff, bias, boff, nullptr, C, nullptr,
            NT_, DFF_, D_, 1, 0, 0, 0, flagp);
    };
    // generator: A f32, out d_out runtime dtype (128x128 tile)
    auto gG = [&](const float* A) {
        dim3 grid(V_ / 128, NT_ / 128, 1);
        if (big) gemm2_kernel<128, 128, 0, 1, 2><<<grid, 256, 0, stream>>>(
            A, Wt, O_GEN, gen_b, 0, nullptr, nullptr, d_out,
            NT_, V_, D_, 0, 0, 0, 0, flagp);
        else     gemm2_kernel<128, 128, 0, 0, 2><<<grid, 256, 0, stream>>>(
            A, gen_w, 0, gen_b, 0, nullptr, nullptr, d_out,
            NT_, V_, D_, 0, 0, 0, 0, flagp);
    };
    auto attn = [&](const unsigned short* Q, const unsigned short* Kq,
                    const unsigned short* Vq, unsigned short* Oq, int causal) {
        dim3 g(S_ / QBLK_, H_, B_);
        if (causal) fattn_kernel<1><<<g, 256, 0, stream>>>(Q, Kq, Vq, Oq);
        else        fattn_kernel<0><<<g, 256, 0, stream>>>(Q, Kq, Vq, Oq);
    };
    auto ln = [&](const float* X, const void* g_, size_t g_off,
                  const void* b_, size_t b_off, float* Y) {
        layernorm_kernel<<<NT_, 256, 0, stream>>>(X, g_, g_off, b_, b_off, Y, flagp);
    };

    // ---- embeddings ----
    embed_kernel<<<(NT_ * D_) / 256, 256, 0, stream>>>(src, src_emb, xbuf, flagp);
    embed_kernel<<<(NT_ * D_) / 256, 256, 0, stream>>>(tgt, tgt_emb, ybuf, flagp);

    // ---- encoder ----
    for (int i = 0; i < L_; ++i) {
        size_t w0 = (size_t)i * 4 * DD;
        size_t b0 = (size_t)i * 4 * D_;
        gP(xbuf, eaw, O_EAW, w0, eab, b0, qb, D_, D_, 3, DD, tokD, D_);
        attn(qb, kb, vb, ab, 0);
        gO(ab, eaw, O_EAW, w0 + 3 * DD, eab, b0 + 3 * D_, xbuf, tbuf, D_, D_);
        ln(tbuf, elg, (size_t)(i * 2 + 0) * D_, elb, (size_t)(i * 2 + 0) * D_, xbuf);
        gF1(xbuf, ew1, O_EW1, (size_t)i * D_ * DFF_, eb1, (size_t)i * DFF_, fb);
        gO(fb, ew2, O_EW2, (size_t)i * DFF_ * D_, eb2, (size_t)i * D_, xbuf, tbuf, D_, DFF_);
        ln(tbuf, elg, (size_t)(i * 2 + 1) * D_, elb, (size_t)(i * 2 + 1) * D_, xbuf);
    }

    // ---- decoder ----
    for (int i = 0; i < L_; ++i) {
        size_t w0 = (size_t)i * 8 * DD;
        size_t b0 = (size_t)i * 8 * D_;
        // masked self-attention (fused QKV)
        gP(ybuf, daw, O_DAW, w0, dab, b0, qb, D_, D_, 3, DD, tokD, D_);
        attn(qb, kb, vb, ab, 1);
        gO(ab, daw, O_DAW, w0 + 3 * DD, dab, b0 + 3 * D_, ybuf, tbuf, D_, D_);
        ln(tbuf, dlg, (size_t)(i * 3 + 0) * D_, dlb, (size_t)(i * 3 + 0) * D_, ybuf);
        // cross-attention: q from y; fused K,V from encoder output x
        gP(ybuf, daw, O_DAW, w0 + 4 * DD, dab, b0 + 4 * D_, qb, D_, D_, 1, 0, 0, 0);
        gP(xbuf, daw, O_DAW, w0 + 5 * DD, dab, b0 + 5 * D_, kb, D_, D_, 2, DD, tokD, D_);
        attn(qb, kb, vb, ab, 0);
        gO(ab, daw, O_DAW, w0 + 7 * DD, dab, b0 + 7 * D_, ybuf, tbuf, D_, D_);
        ln(tbuf, dlg, (size_t)(i * 3 + 1) * D_, dlb, (size_t)(i * 3 + 1) * D_, ybuf);
        // FFN
        gF1(ybuf, dw1, O_DW1, (size_t)i * D_ * DFF_, db1, (size_t)i * DFF_, fb);
        gO(fb, dw2, O_DW2, (size_t)i * DFF_ * D_, db2, (size_t)i * D_, ybuf, tbuf, D_, DFF_);
        ln(tbuf, dlg, (size_t)(i * 3 + 2) * D_, dlb, (size_t)(i * 3 + 2) * D_, ybuf);
    }

    // ---- generator -> d_out ----
    gG(ybuf);
}

// Round 5
// 3175.855 us; speedup vs baseline: 7.0303x; 1.0200x over previous
//
#include <hip/hip_runtime.h>
#include <hip/hip_bf16.h>
#include <math.h>

typedef __hip_bfloat16 bf16;
typedef __attribute__((ext_vector_type(8))) short          s16x8;   // MFMA a/b frag (8 bf16)
typedef __attribute__((ext_vector_type(8))) unsigned short u16x8;
typedef __attribute__((ext_vector_type(4))) float          f32x4;   // MFMA acc

#define B_   4
#define S_   1024
#define D_   512
#define H_   8
#define DK_  64
#define DFF_ 2048
#define L_   6
#define V_   16000
#define NT_  (B_ * S_)   // 4096 tokens

// Runtime dtype flag: 1 if float tensors are bf16 on device, 0 if f32.
__global__ void detect_kernel(const void* __restrict__ g, int* __restrict__ flag)
{
    const unsigned short* u = (const unsigned short*)g;
    *flag = (u[0] == 0x3F80 && u[1] == 0x3F80) ? 1 : 0;
}

__device__ __forceinline__ float ldw(const void* p, size_t i, int isbf)
{
    if (isbf) return __bfloat162float(((const bf16*)p)[i]);
    return ((const float*)p)[i];
}

// f32 -> bf16 bits, round-to-nearest-even
__device__ __forceinline__ unsigned short f2b(float f)
{
    unsigned int u = __float_as_uint(f);
    return (unsigned short)((u + 0x7FFFu + ((u >> 16) & 1u)) >> 16);
}
__device__ __forceinline__ float b2f(unsigned short u)
{
    return __uint_as_float((unsigned int)u << 16);
}

// async global->LDS, 16 B per lane; LDS dest = wave-uniform base + lane*16
__device__ __forceinline__ void gl_lds16(const unsigned short* g, unsigned short* l)
{
    __builtin_amdgcn_global_load_lds(
        (const __attribute__((address_space(1))) unsigned int*)g,
        (__attribute__((address_space(3))) unsigned int*)l, 16, 0, 0);
}

// ---------------------------------------------------------------------------
// Embedding + positional encoding: f32 out + bf16 mirror (GEMM A-input)
// ---------------------------------------------------------------------------
__global__ __launch_bounds__(256)
void embed_kernel(const int* __restrict__ tok, const void* __restrict__ emb,
                  float* __restrict__ X, unsigned short* __restrict__ Xb,
                  const int* __restrict__ flagp)
{
    const int isbf = *flagp;
    int idx = blockIdx.x * 256 + threadIdx.x;
    int d  = idx & (D_ - 1);
    int bs = idx >> 9;
    int s  = bs & (S_ - 1);
    int t  = tok[bs];
    float e = ldw(emb, (size_t)t * D_ + d, isbf);
    float expo = (float)(d & ~1) * (1.0f / (float)D_);
    float div  = powf(10000.0f, expo);
    float arg  = (float)s / div;
    float pe   = (d & 1) ? cosf(arg) : sinf(arg);
    float v = e + pe;
    X[idx]  = v;
    Xb[idx] = f2b(v);
}

// ---------------------------------------------------------------------------
// Weight preconvert + transpose: W[z][K][N] (flag dtype) -> Wt[z][N][K] bf16.
// ---------------------------------------------------------------------------
__global__ __launch_bounds__(256)
void wconv_kernel(const void* __restrict__ W, unsigned short* __restrict__ Wt,
                  int K, int N, const int* __restrict__ flagp)
{
    __shared__ unsigned short T[64 * 72];
    const int isbf = *flagp;
    const int tid = threadIdx.x;
    const int n0 = blockIdx.x * 64, k0 = blockIdx.y * 64;
    const size_t mb = (size_t)blockIdx.z * K * N;
#pragma unroll
    for (int i = 0; i < 16; ++i) {
        int idx = i * 256 + tid;
        int kk = idx >> 6, n = idx & 63;
        unsigned short v;
        if (isbf) v = ((const unsigned short*)W)[mb + (size_t)(k0 + kk) * N + n0 + n];
        else      v = f2b(((const float*)W)[mb + (size_t)(k0 + kk) * N + n0 + n]);
        T[n * 72 + kk] = v;
    }
    __syncthreads();
#pragma unroll
    for (int j = 0; j < 2; ++j) {
        int unit = j * 256 + tid;
        int n = unit >> 3, q = unit & 7;
        *(u16x8*)&Wt[mb + (size_t)(n0 + n) * K + k0 + q * 8] =
            *(const u16x8*)&T[n * 72 + q * 8];
    }
}

// ---------------------------------------------------------------------------
// MFMA GEMM v3 (big path): C[M,N] = A[M,K]bf16 * Wt[z][N][K]bf16 + bias
//   [+res f32] [relu].  OB: 0 = f32 C, 1 = bf16 C, 2 = d_out runtime dtype.
//   - 256 thr = 4 waves 2x2; wave tile (BM/2)x(BN/2); BK=32.
//   - Staging via global_load_lds width-16 (zero VALU, no VGPR round-trip).
//   - LDS rows: 32 ushorts (64 B), 4 slots of 16 B, rotation-swizzled
//     slot' = (slot + (row>>1)) & 3  -> ds_read_b128 frag reads are 2-way
//     bank-aliased (free).  Linear LDS dest + inverse-swizzled global source.
//   - Frags: A,B read [row][k]: row=lane&15, k=(lane>>4)*8; C/D: col=lane&15,
//     row=(lane>>4)*4+reg.  blockIdx.x = M-panel (consecutive blocks share
//     the Wt tile -> L2/L3 reuse), blockIdx.z batches weights (QKV).
// ---------------------------------------------------------------------------
template<int BM, int BN, int OB>
__global__ __launch_bounds__(256)
void gemm3_kernel(const unsigned short* __restrict__ A,
                  const unsigned short* __restrict__ Wt, size_t w_off,
                  const void* __restrict__ bias, size_t b_off,
                  const float* __restrict__ res,
                  void* __restrict__ C, void* __restrict__ Cout,
                  int M, int N, int K, int relu,
                  size_t sW, size_t sO, size_t sB,
                  const int* __restrict__ flagp)
{
    constexpr int FM = BM / 32;
    constexpr int FN = BN / 32;
    __shared__ __align__(16) unsigned short As[BM * 32];
    __shared__ __align__(16) unsigned short Bs[BN * 32];

    const int isbf = *flagp;
    const int tid  = threadIdx.x;
    const int lane = tid & 63;
    const int wv   = tid >> 6;
    const int wr   = wv >> 1, wc = wv & 1;
    const int l15  = lane & 15, g = lane >> 4;
    const int sr   = lane >> 2;            // staging: row-within-16
    const int sp   = lane & 3;             // staging: lds slot
    const int row0 = blockIdx.x * BM;      // M on x: share Wt tile
    const int col0 = blockIdx.y * BN;
    const int z    = blockIdx.z;
    const size_t wbase = w_off + (size_t)z * sW;

    f32x4 acc[FM][FN];
#pragma unroll
    for (int i = 0; i < FM; ++i)
#pragma unroll
        for (int j = 0; j < FN; ++j)
            acc[i][j] = (f32x4){0.f, 0.f, 0.f, 0.f};

    for (int k0 = 0; k0 < K; k0 += 32) {
        // ---- stage A: wave wv covers 16 rows per pass, 1024 B linear ----
#pragma unroll
        for (int u = 0; u < BM / 64; ++u) {
            int r0 = u * 64 + wv * 16;
            int r  = r0 + sr;
            int q  = (sp - (r >> 1)) & 3;          // inverse swizzle on source
            gl_lds16(A + (size_t)(row0 + r) * K + k0 + q * 8, As + r0 * 32);
        }
        // ---- stage B ----
#pragma unroll
        for (int u = 0; u < BN / 64; ++u) {
            int r0 = u * 64 + wv * 16;
            int n  = r0 + sr;
            int q  = (sp - (n >> 1)) & 3;
            gl_lds16(Wt + wbase + (size_t)(col0 + n) * K + k0 + q * 8, Bs + r0 * 32);
        }
        __syncthreads();                            // drains vmcnt

        // ---- fragments (swizzled read) + MFMA ----
        s16x8 af[FM], bfr[FN];
#pragma unroll
        for (int mi = 0; mi < FM; ++mi) {
            int r = wr * (BM / 2) + mi * 16 + l15;
            af[mi] = *(const s16x8*)&As[r * 32 + ((g + (r >> 1)) & 3) * 8];
        }
#pragma unroll
        for (int ni = 0; ni < FN; ++ni) {
            int c = wc * (BN / 2) + ni * 16 + l15;
            bfr[ni] = *(const s16x8*)&Bs[c * 32 + ((g + (c >> 1)) & 3) * 8];
        }
#pragma unroll
        for (int mi = 0; mi < FM; ++mi)
#pragma unroll
            for (int ni = 0; ni < FN; ++ni)
                acc[mi][ni] = __builtin_amdgcn_mfma_f32_16x16x32_bf16(
                    af[mi], bfr[ni], acc[mi][ni], 0, 0, 0);
        __syncthreads();
    }

    // ---- epilogue ----
#pragma unroll
    for (int mi = 0; mi < FM; ++mi) {
#pragma unroll
        for (int ni = 0; ni < FN; ++ni) {
            int n = col0 + wc * (BN / 2) + ni * 16 + l15;
            float bv = ldw(bias, b_off + (size_t)z * sB + n, isbf);
#pragma unroll
            for (int q = 0; q < 4; ++q) {
                int m = row0 + wr * (BM / 2) + mi * 16 + g * 4 + q;
                float v = acc[mi][ni][q] + bv;
                size_t oidx = (size_t)m * N + n;
                if (res)  v += res[oidx];
                if (relu) v = fmaxf(v, 0.f);
                if (OB == 0)      ((float*)C + (size_t)z * sO)[oidx] = v;
                else if (OB == 1) ((unsigned short*)C + (size_t)z * sO)[oidx] = f2b(v);
                else {
                    if (isbf) ((bf16*)Cout)[oidx] = __float2bfloat16(v);
                    else      ((float*)Cout)[oidx] = v;
                }
            }
        }
    }
}

// ---------------------------------------------------------------------------
// MFMA GEMM v2 (small-ws fallback, round-2-verified structure). A bf16.
// WT=0: B strided from original W (flag dtype).
// ---------------------------------------------------------------------------
template<int BM, int BN, int OB>
__global__ __launch_bounds__(256)
void gemm2_kernel(const unsigned short* __restrict__ A,
                  const void* __restrict__ W, size_t w_off,
                  const void* __restrict__ bias, size_t b_off,
                  const float* __restrict__ res,
                  void* __restrict__ C, void* __restrict__ Cout,
                  int M, int N, int K, int relu,
                  size_t sW, size_t sO, size_t sB,
                  const int* __restrict__ flagp)
{
    constexpr int ROWU = 40;
    constexpr int FM = BM / 32;
    constexpr int FN = BN / 32;
    __shared__ __align__(16) unsigned short As[BM * ROWU];
    __shared__ __align__(16) unsigned short Bs[BN * ROWU];

    const int isbf = *flagp;
    const int tid  = threadIdx.x;
    const int lane = tid & 63;
    const int wid  = tid >> 6;
    const int wr   = wid >> 1, wc = wid & 1;
    const int l15  = lane & 15, g = lane >> 4;
    const int row0 = blockIdx.y * BM;
    const int col0 = blockIdx.x * BN;
    const int z    = blockIdx.z;
    const size_t wbase = w_off + (size_t)z * sW;

    f32x4 acc[FM][FN];
#pragma unroll
    for (int i = 0; i < FM; ++i)
#pragma unroll
        for (int j = 0; j < FN; ++j)
            acc[i][j] = (f32x4){0.f, 0.f, 0.f, 0.f};

    for (int k0 = 0; k0 < K; k0 += 32) {
#pragma unroll
        for (int u = 0; u < BM / 64; ++u) {
            int unit = tid + u * 256;
            int r = unit >> 2, q = unit & 3;
            *(u16x8*)&As[r * ROWU + q * 8] =
                *(const u16x8*)(A + (size_t)(row0 + r) * K + k0 + q * 8);
        }
#pragma unroll
        for (int u = 0; u < (BN * 4) / 256; ++u) {
            int unit = tid + u * 256;
            int n = unit >> 2, q = unit & 3;
            u16x8 v;
            if (isbf) {
                const unsigned short* wp = (const unsigned short*)W;
#pragma unroll
                for (int j = 0; j < 8; ++j)
                    v[j] = wp[wbase + (size_t)(k0 + q * 8 + j) * N + col0 + n];
            } else {
                const float* wp = (const float*)W;
#pragma unroll
                for (int j = 0; j < 8; ++j)
                    v[j] = f2b(wp[wbase + (size_t)(k0 + q * 8 + j) * N + col0 + n]);
            }
            *(u16x8*)&Bs[n * ROWU + q * 8] = v;
        }
        __syncthreads();

        s16x8 af[FM], bfr[FN];
#pragma unroll
        for (int mi = 0; mi < FM; ++mi) {
            int r = wr * (BM / 2) + mi * 16 + l15;
            af[mi] = *(const s16x8*)&As[r * ROWU + g * 8];
        }
#pragma unroll
        for (int ni = 0; ni < FN; ++ni) {
            int c = wc * (BN / 2) + ni * 16 + l15;
            bfr[ni] = *(const s16x8*)&Bs[c * ROWU + g * 8];
        }
#pragma unroll
        for (int mi = 0; mi < FM; ++mi)
#pragma unroll
            for (int ni = 0; ni < FN; ++ni)
                acc[mi][ni] = __builtin_amdgcn_mfma_f32_16x16x32_bf16(
                    af[mi], bfr[ni], acc[mi][ni], 0, 0, 0);
        __syncthreads();
    }

#pragma unroll
    for (int mi = 0; mi < FM; ++mi) {
#pragma unroll
        for (int ni = 0; ni < FN; ++ni) {
            int n = col0 + wc * (BN / 2) + ni * 16 + l15;
            float bv = ldw(bias, b_off + (size_t)z * sB + n, isbf);
#pragma unroll
            for (int q = 0; q < 4; ++q) {
                int m = row0 + wr * (BM / 2) + mi * 16 + g * 4 + q;
                float v = acc[mi][ni][q] + bv;
                size_t oidx = (size_t)m * N + n;
                if (res)  v += res[oidx];
                if (relu) v = fmaxf(v, 0.f);
                if (OB == 0)      ((float*)C + (size_t)z * sO)[oidx] = v;
                else if (OB == 1) ((unsigned short*)C + (size_t)z * sO)[oidx] = f2b(v);
                else {
                    if (isbf) ((bf16*)Cout)[oidx] = __float2bfloat16(v);
                    else      ((float*)Cout)[oidx] = v;
                }
            }
        }
    }
}

// ---------------------------------------------------------------------------
// Flash attention (MFMA bf16). Q/K/V/O bf16 [B,S,H,DK]. (round-2-verified)
// ---------------------------------------------------------------------------
#define QBLK_ 64
#define KVB_  64
#define LROW_ 72

template<int CAUSAL>
__global__ __launch_bounds__(256)
void fattn_kernel(const unsigned short* __restrict__ Q,
                  const unsigned short* __restrict__ Kp,
                  const unsigned short* __restrict__ Vp,
                  unsigned short* __restrict__ O)
{
    __shared__ __align__(16) unsigned short Ks[64 * LROW_];
    __shared__ __align__(16) unsigned short Vt[64 * LROW_];
    __shared__ __align__(16) unsigned short QP[64 * LROW_];  // Q, then P

    const int q0  = blockIdx.x * QBLK_;
    const int h   = blockIdx.y, b = blockIdx.z;
    const int tid = threadIdx.x;
    const int lane = tid & 63, w = tid >> 6;
    const int l15 = lane & 15, g = lane >> 4;

    {
        int r = tid >> 2, c = (tid & 3) * 16;
        const unsigned short* qp = Q + ((size_t)(b * S_ + q0 + r) * H_ + h) * DK_ + c;
        u16x8 v0 = *(const u16x8*)qp, v1 = *(const u16x8*)(qp + 8);
#pragma unroll
        for (int j = 0; j < 8; ++j) v0[j] = f2b(b2f(v0[j]) * 0.125f);
#pragma unroll
        for (int j = 0; j < 8; ++j) v1[j] = f2b(b2f(v1[j]) * 0.125f);
        *(u16x8*)&QP[r * LROW_ + c]     = v0;
        *(u16x8*)&QP[r * LROW_ + c + 8] = v1;
    }
    __syncthreads();
    s16x8 aq0 = *(const s16x8*)&QP[(w * 16 + l15) * LROW_ + g * 8];
    s16x8 aq1 = *(const s16x8*)&QP[(w * 16 + l15) * LROW_ + 32 + g * 8];

    float m[4] = {-INFINITY, -INFINITY, -INFINITY, -INFINITY};
    float l[4] = {0.f, 0.f, 0.f, 0.f};
    f32x4 o[4];
#pragma unroll
    for (int ni = 0; ni < 4; ++ni) o[ni] = (f32x4){0.f, 0.f, 0.f, 0.f};

    const int nt = CAUSAL ? (q0 / KVB_ + 1) : (S_ / KVB_);
    for (int t = 0; t < nt; ++t) {
        const int j0 = t * KVB_;
        {
            int r = tid >> 2, c = (tid & 3) * 16;
            const unsigned short* kp = Kp + ((size_t)(b * S_ + j0 + r) * H_ + h) * DK_ + c;
            *(u16x8*)&Ks[r * LROW_ + c]     = *(const u16x8*)kp;
            *(u16x8*)&Ks[r * LROW_ + c + 8] = *(const u16x8*)(kp + 8);
        }
        {
            int d = tid & 63, kq = tid >> 6;
            const unsigned short* vp = Vp + ((size_t)(b * S_ + j0 + kq * 16) * H_ + h) * DK_ + d;
            u16x8 v0, v1;
#pragma unroll
            for (int j = 0; j < 8; ++j) v0[j] = vp[(size_t)j * (H_ * DK_)];
#pragma unroll
            for (int j = 0; j < 8; ++j) v1[j] = vp[(size_t)(8 + j) * (H_ * DK_)];
            *(u16x8*)&Vt[d * LROW_ + kq * 16]     = v0;
            *(u16x8*)&Vt[d * LROW_ + kq * 16 + 8] = v1;
        }
        __syncthreads();

        f32x4 sc[4];
#pragma unroll
        for (int ni = 0; ni < 4; ++ni) {
            s16x8 bk0 = *(const s16x8*)&Ks[(ni * 16 + l15) * LROW_ + g * 8];
            s16x8 bk1 = *(const s16x8*)&Ks[(ni * 16 + l15) * LROW_ + 32 + g * 8];
            f32x4 a = (f32x4){0.f, 0.f, 0.f, 0.f};
            a = __builtin_amdgcn_mfma_f32_16x16x32_bf16(aq0, bk0, a, 0, 0, 0);
            a = __builtin_amdgcn_mfma_f32_16x16x32_bf16(aq1, bk1, a, 0, 0, 0);
            sc[ni] = a;
        }
        if (CAUSAL && (j0 + KVB_ > q0)) {
#pragma unroll
            for (int ni = 0; ni < 4; ++ni)
#pragma unroll
                for (int r = 0; r < 4; ++r) {
                    int qrow = q0 + w * 16 + g * 4 + r;
                    int col  = j0 + ni * 16 + l15;
                    if (col > qrow) sc[ni][r] = -INFINITY;
                }
        }
        float pr[4][4];
#pragma unroll
        for (int r = 0; r < 4; ++r) {
            float mt = fmaxf(fmaxf(sc[0][r], sc[1][r]), fmaxf(sc[2][r], sc[3][r]));
#pragma unroll
            for (int sft = 1; sft < 16; sft <<= 1)
                mt = fmaxf(mt, __shfl_xor(mt, sft, 64));
            float mn = fmaxf(m[r], mt);
            float rescale = __expf(m[r] - mn);
            float rs = 0.f;
#pragma unroll
            for (int ni = 0; ni < 4; ++ni) {
                float p = __expf(sc[ni][r] - mn);
                pr[ni][r] = p;
                rs += p;
            }
#pragma unroll
            for (int sft = 1; sft < 16; sft <<= 1)
                rs += __shfl_xor(rs, sft, 64);
            l[r] = l[r] * rescale + rs;
            m[r] = mn;
#pragma unroll
            for (int ni = 0; ni < 4; ++ni) o[ni][r] *= rescale;
        }
#pragma unroll
        for (int ni = 0; ni < 4; ++ni)
#pragma unroll
            for (int r = 0; r < 4; ++r)
                QP[(w * 16 + g * 4 + r) * LROW_ + ni * 16 + l15] = f2b(pr[ni][r]);
        s16x8 pa0 = *(const s16x8*)&QP[(w * 16 + l15) * LROW_ + g * 8];
        s16x8 pa1 = *(const s16x8*)&QP[(w * 16 + l15) * LROW_ + 32 + g * 8];
#pragma unroll
        for (int ni = 0; ni < 4; ++ni) {
            s16x8 vb0 = *(const s16x8*)&Vt[(ni * 16 + l15) * LROW_ + g * 8];
            s16x8 vb1 = *(const s16x8*)&Vt[(ni * 16 + l15) * LROW_ + 32 + g * 8];
            o[ni] = __builtin_amdgcn_mfma_f32_16x16x32_bf16(pa0, vb0, o[ni], 0, 0, 0);
            o[ni] = __builtin_amdgcn_mfma_f32_16x16x32_bf16(pa1, vb1, o[ni], 0, 0, 0);
        }
        __syncthreads();
    }

#pragma unroll
    for (int r = 0; r < 4; ++r) {
        float inv = 1.0f / l[r];
        int qrow = q0 + w * 16 + g * 4 + r;
        unsigned short* op = O + ((size_t)(b * S_ + qrow) * H_ + h) * DK_;
#pragma unroll
        for (int ni = 0; ni < 4; ++ni)
            op[ni * 16 + l15] = f2b(o[ni][r] * inv);
    }
}

// ---------------------------------------------------------------------------
// LayerNorm over rows of 512: f32 out + bf16 mirror. eps = 1e-5.
// ---------------------------------------------------------------------------
__global__ __launch_bounds__(256)
void layernorm_kernel(const float* __restrict__ X,
                      const void* __restrict__ g, size_t g_off,
                      const void* __restrict__ bb, size_t b_off,
                      float* __restrict__ Y, unsigned short* __restrict__ Yb,
                      const int* __restrict__ flagp)
{
    __shared__ float red[256];
    const int isbf = *flagp;
    const int row = blockIdx.x, tid = threadIdx.x;
    const float* x = X + (size_t)row * D_;
    float v0 = x[tid], v1 = x[tid + 256];
    red[tid] = v0 + v1;
    __syncthreads();
    for (int s = 128; s > 0; s >>= 1) {
        if (tid < s) red[tid] += red[tid + s];
        __syncthreads();
    }
    float mean = red[0] * (1.0f / (float)D_);
    __syncthreads();
    float d0 = v0 - mean, d1 = v1 - mean;
    red[tid] = d0 * d0 + d1 * d1;
    __syncthreads();
    for (int s = 128; s > 0; s >>= 1) {
        if (tid < s) red[tid] += red[tid + s];
        __syncthreads();
    }
    float r = rsqrtf(red[0] * (1.0f / (float)D_) + 1e-5f);
    float y0 = ldw(g, g_off + tid, isbf)       * d0 * r + ldw(bb, b_off + tid, isbf);
    float y1 = ldw(g, g_off + tid + 256, isbf) * d1 * r + ldw(bb, b_off + tid + 256, isbf);
    float* y = Y + (size_t)row * D_;
    unsigned short* yb = Yb + (size_t)row * D_;
    y[tid]        = y0;
    y[tid + 256]  = y1;
    yb[tid]       = f2b(y0);
    yb[tid + 256] = f2b(y1);
}

// ---------------------------------------------------------------------------
extern "C" void kernel_launch(void* const* d_in, const int* in_sizes, int n_in,
                              void* d_out, int out_size, void* d_ws, size_t ws_size,
                              hipStream_t stream)
{
    (void)in_sizes; (void)n_in; (void)out_size;

    const int*  src      = (const int*)d_in[0];
    const int*  tgt      = (const int*)d_in[1];
    const void* src_emb  = d_in[3];
    const void* tgt_emb  = d_in[4];
    const void* eaw      = d_in[5];   // [L,4,D,D]
    const void* eab      = d_in[6];
    const void* ew1      = d_in[7];   // [L,D,DFF]
    const void* eb1      = d_in[8];
    const void* ew2      = d_in[9];   // [L,DFF,D]
    const void* eb2      = d_in[10];
    const void* elg      = d_in[11];
    const void* elb      = d_in[12];
    const void* daw      = d_in[13];  // [L,8,D,D]
    const void* dab      = d_in[14];
    const void* dw1      = d_in[15];
    const void* db1      = d_in[16];
    const void* dw2      = d_in[17];
    const void* db2      = d_in[18];
    const void* dlg      = d_in[19];
    const void* dlb      = d_in[20];
    const void* gen_w    = d_in[21];  // [D,V]
    const void* gen_b    = d_in[22];

    const size_t tokD = (size_t)NT_ * D_;          // 2,097,152
    const size_t tokF = (size_t)NT_ * DFF_;        // 8,388,608
    const size_t DD   = (size_t)D_ * D_;           // 262,144

    // Wt region layout (elems)
    const size_t O_EAW = 0;
    const size_t O_EW1 = O_EAW + 24ULL * DD;
    const size_t O_EW2 = O_EW1 + 6ULL * D_ * DFF_;
    const size_t O_DAW = O_EW2 + 6ULL * DFF_ * D_;
    const size_t O_DW1 = O_DAW + 48ULL * DD;
    const size_t O_DW2 = O_DW1 + 6ULL * D_ * DFF_;
    const size_t O_GEN = O_DW2 + 6ULL * DFF_ * D_;
    const size_t WTELEMS = O_GEN + (size_t)D_ * V_;    // 52,232,192

    // workspace carve-up.  fb (FFN mid) aliases qkv+ab: never live together.
    size_t off = 256;
    int*   flagp = (int*)d_ws;
    float* xbuf = (float*)((char*)d_ws + off); off += tokD * 4;
    float* ybuf = (float*)((char*)d_ws + off); off += tokD * 4;
    float* tbuf = (float*)((char*)d_ws + off); off += tokD * 4;
    unsigned short* xb16 = (unsigned short*)((char*)d_ws + off); off += tokD * 2;
    unsigned short* yb16 = (unsigned short*)((char*)d_ws + off); off += tokD * 2;
    unsigned short* qb = (unsigned short*)((char*)d_ws + off);   // fb aliases here
    unsigned short* fb = qb;
    unsigned short* kb = qb + tokD;
    unsigned short* vb = kb + tokD;
    unsigned short* ab = vb + tokD;
    off += tokF * 2;                                   // = 4 * tokD * 2
    const size_t need_small = off;
    unsigned short* Wt = (unsigned short*)((char*)d_ws + off); off += WTELEMS * 2;
    const size_t need_big = off;

    if (ws_size < need_small) return;              // visible failure, no OOB
    const bool big = (ws_size >= need_big);

    detect_kernel<<<1, 1, 0, stream>>>(elg, flagp);

    // ---- one-time weight preconvert + transpose (big path) ----
    if (big) {
        auto wc = [&](const void* W, size_t dstoff, int K, int N, int z) {
            dim3 g(N / 64, K / 64, z);
            wconv_kernel<<<g, 256, 0, stream>>>(W, Wt + dstoff, K, N, flagp);
        };
        wc(eaw,   O_EAW, 512, 512,   24);
        wc(ew1,   O_EW1, 512, 2048,  6);
        wc(ew2,   O_EW2, 2048, 512,  6);
        wc(daw,   O_DAW, 512, 512,   48);
        wc(dw1,   O_DW1, 512, 2048,  6);
        wc(dw2,   O_DW2, 2048, 512,  6);
        wc(gen_w, O_GEN, 512, 16000, 1);
    }

    // ---- GEMM launchers ----
    // projections (N=512): A bf16 mirror, out bf16 ws
    auto gP = [&](const unsigned short* A, const void* Wf, size_t roff, size_t woff,
                  const void* bias, size_t boff, unsigned short* C,
                  int K, int nz, size_t sW, size_t sO, size_t sB) {
        if (big) {
            dim3 grid(NT_ / 128, 512 / 64, nz);
            gemm3_kernel<128, 64, 1><<<grid, 256, 0, stream>>>(
                A, Wt, roff + woff, bias, boff, nullptr, C, nullptr,
                NT_, 512, K, 0, sW, sO, sB, flagp);
        } else {
            dim3 grid(512 / 64, NT_ / 64, nz);
            gemm2_kernel<64, 64, 1><<<grid, 256, 0, stream>>>(
                A, Wf, woff, bias, boff, nullptr, C, nullptr,
                NT_, 512, K, 0, sW, sO, sB, flagp);
        }
    };
    // out-proj / FFN2 (N=512): A bf16 ws, res f32, out f32 ws
    auto gO = [&](const unsigned short* A, const void* Wf, size_t roff, size_t woff,
                  const void* bias, size_t boff, const float* res, float* C, int K) {
        if (big) {
            dim3 grid(NT_ / 128, 512 / 64, 1);
            gemm3_kernel<128, 64, 0><<<grid, 256, 0, stream>>>(
                A, Wt, roff + woff, bias, boff, res, C, nullptr,
                NT_, 512, K, 0, 0, 0, 0, flagp);
        } else {
            dim3 grid(512 / 64, NT_ / 64, 1);
            gemm2_kernel<64, 64, 0><<<grid, 256, 0, stream>>>(
                A, Wf, woff, bias, boff, res, C, nullptr,
                NT_, 512, K, 0, 0, 0, 0, flagp);
        }
    };
    // FFN1 (N=2048): A bf16 mirror, relu, out bf16 ws
    auto gF1 = [&](const unsigned short* A, const void* Wf, size_t roff, size_t woff,
                   const void* bias, size_t boff, unsigned short* C) {
        if (big) {
            dim3 grid(NT_ / 128, DFF_ / 128, 1);
            gemm3_kernel<128, 128, 1><<<grid, 256, 0, stream>>>(
                A, Wt, roff + woff, bias, boff, nullptr, C, nullptr,
                NT_, DFF_, D_, 1, 0, 0, 0, flagp);
        } else {
            dim3 grid(DFF_ / 128, NT_ / 128, 1);
            gemm2_kernel<128, 128, 1><<<grid, 256, 0, stream>>>(
                A, Wf, woff, bias, boff, nullptr, C, nullptr,
                NT_, DFF_, D_, 1, 0, 0, 0, flagp);
        }
    };
    // generator: A bf16 mirror, out d_out runtime dtype
    auto gG = [&](const unsigned short* A) {
        if (big) {
            dim3 grid(NT_ / 128, V_ / 128, 1);
            gemm3_kernel<128, 128, 2><<<grid, 256, 0, stream>>>(
                A, Wt, O_GEN, gen_b, 0, nullptr, nullptr, d_out,
                NT_, V_, D_, 0, 0, 0, 0, flagp);
        } else {
            dim3 grid(V_ / 128, NT_ / 128, 1);
            gemm2_kernel<128, 128, 2><<<grid, 256, 0, stream>>>(
                A, gen_w, 0, gen_b, 0, nullptr, nullptr, d_out,
                NT_, V_, D_, 0, 0, 0, 0, flagp);
        }
    };
    auto attn = [&](const unsigned short* Q, const unsigned short* Kq,
                    const unsigned short* Vq, unsigned short* Oq, int causal) {
        dim3 g(S_ / QBLK_, H_, B_);
        if (causal) fattn_kernel<1><<<g, 256, 0, stream>>>(Q, Kq, Vq, Oq);
        else        fattn_kernel<0><<<g, 256, 0, stream>>>(Q, Kq, Vq, Oq);
    };
    auto ln = [&](const float* X, const void* g_, size_t g_off,
                  const void* b_, size_t b_off, float* Y, unsigned short* Yb) {
        layernorm_kernel<<<NT_, 256, 0, stream>>>(X, g_, g_off, b_, b_off, Y, Yb, flagp);
    };

    // ---- embeddings (f32 + bf16 mirror) ----
    embed_kernel<<<(NT_ * D_) / 256, 256, 0, stream>>>(src, src_emb, xbuf, xb16, flagp);
    embed_kernel<<<(NT_ * D_) / 256, 256, 0, stream>>>(tgt, tgt_emb, ybuf, yb16, flagp);

    // ---- encoder ----
    for (int i = 0; i < L_; ++i) {
        size_t w0 = (size_t)i * 4 * DD;
        size_t b0 = (size_t)i * 4 * D_;
        gP(xb16, eaw, O_EAW, w0, eab, b0, qb, D_, 3, DD, tokD, D_);
        attn(qb, kb, vb, ab, 0);
        gO(ab, eaw, O_EAW, w0 + 3 * DD, eab, b0 + 3 * D_, xbuf, tbuf, D_);
        ln(tbuf, elg, (size_t)(i * 2 + 0) * D_, elb, (size_t)(i * 2 + 0) * D_, xbuf, xb16);
        gF1(xb16, ew1, O_EW1, (size_t)i * D_ * DFF_, eb1, (size_t)i * DFF_, fb);
        gO(fb, ew2, O_EW2, (size_t)i * DFF_ * D_, eb2, (size_t)i * D_, xbuf, tbuf, DFF_);
        ln(tbuf, elg, (size_t)(i * 2 + 1) * D_, elb, (size_t)(i * 2 + 1) * D_, xbuf, xb16);
    }

    // ---- decoder ----
    for (int i = 0; i < L_; ++i) {
        size_t w0 = (size_t)i * 8 * DD;
        size_t b0 = (size_t)i * 8 * D_;
        // masked self-attention (fused QKV)
        gP(yb16, daw, O_DAW, w0, dab, b0, qb, D_, 3, DD, tokD, D_);
        attn(qb, kb, vb, ab, 1);
        gO(ab, daw, O_DAW, w0 + 3 * DD, dab, b0 + 3 * D_, ybuf, tbuf, D_);
        ln(tbuf, dlg, (size_t)(i * 3 + 0) * D_, dlb, (size_t)(i * 3 + 0) * D_, ybuf, yb16);
        // cross-attention: q from y; fused K,V from encoder output x
        gP(yb16, daw, O_DAW, w0 + 4 * DD, dab, b0 + 4 * D_, qb, D_, 1, 0, 0, 0);
        gP(xb16, daw, O_DAW, w0 + 5 * DD, dab, b0 + 5 * D_, kb, D_, 2, DD, tokD, D_);
        attn(qb, kb, vb, ab, 0);
        gO(ab, daw, O_DAW, w0 + 7 * DD, dab, b0 + 7 * D_, ybuf, tbuf, D_);
        ln(tbuf, dlg, (size_t)(i * 3 + 1) * D_, dlb, (size_t)(i * 3 + 1) * D_, ybuf, yb16);
        // FFN
        gF1(yb16, dw1, O_DW1, (size_t)i * D_ * DFF_, db1, (size_t)i * DFF_, fb);
        gO(fb, dw2, O_DW2, (size_t)i * DFF_ * D_, db2, (size_t)i * D_, ybuf, tbuf, DFF_);
        ln(tbuf, dlg, (size_t)(i * 3 + 2) * D_, dlb, (size_t)(i * 3 + 2) * D_, ybuf, yb16);
    }

    // ---- generator -> d_out ----
    gG(yb16);
}